// Round 1
// baseline (216.794 us; speedup 1.0000x reference)
//
#include <hip/hip_runtime.h>
#include <hip/hip_bf16.h>
#include <stdint.h>

typedef unsigned short u16;
typedef __attribute__((ext_vector_type(8))) short s16x8;
typedef __attribute__((ext_vector_type(4))) float f32x4;
typedef __attribute__((ext_vector_type(4))) unsigned short u16x4;

static constexpr int B_ = 8, C_ = 512, N_ = 1024, G_ = 8;
static constexpr float EPS = 1e-5f;

// ---------------- workspace layout (bytes) ----------------
static constexpr size_t OFF_XN  = 0;                    // f32 [B][C][N]   16 MB (residual)
static constexpr size_t OFF_XNT = 16777216;             // bf16 [B][N][C]   8 MB (GEMM A)
static constexpr size_t OFF_QF  = 25165824;             // f32 [B][N][C]   16 MB (q pre-softmax; reused as out2)
static constexpr size_t OFF_K   = 41943040;             // bf16 [B][N][C]   8 MB (k, softmaxed in place)
static constexpr size_t OFF_V   = 50331648;             // bf16 [B][N][C]   8 MB
static constexpr size_t OFF_QS  = 58720256;             // bf16 [B][N][C]   8 MB (q post-softmax)
static constexpr size_t OFF_CTX = 67108864;             // bf16 [B][C][C]   4 MB
static constexpr size_t OFF_ATT = 71303168;             // bf16 [B][N][C]   8 MB
static constexpr size_t OFF_WQ  = 79691776;             // bf16 [1536][512] 1.5 MB
static constexpr size_t OFF_WP  = 81264640;             // bf16 [512][512]  0.5 MB
static constexpr size_t OFF_GNP = 81788928;             // f32 [64][8][2]   4 KB  (groupnorm partials)
static constexpr size_t OFF_QMS = 81793024;             // f32 [B][C][8][2] 256 KB (q-softmax partials)

// ---------------- helpers ----------------
__device__ __forceinline__ float b2f(u16 u) {
  union { float f; uint32_t i; } x; x.i = ((uint32_t)u) << 16; return x.f;
}
__device__ __forceinline__ u16 f2b(float f) {
  union { float f; uint32_t i; } x; x.f = f;
  return (u16)((x.i + 0x7fffu + ((x.i >> 16) & 1u)) >> 16);
}
#define AS1 __attribute__((address_space(1)))
#define AS3 __attribute__((address_space(3)))
__device__ __forceinline__ void gl2lds16(const void* g, void* l) {
  __builtin_amdgcn_global_load_lds((const AS1 void*)g, (AS3 void*)l, 16, 0, 0);
}

// ---------------- groupnorm ----------------
__global__ __launch_bounds__(256) void gn_partial(const float* __restrict__ x,
                                                  float* __restrict__ gnp) {
  int bg = blockIdx.x;      // 64 = B*G (each group's 64ch x 1024 spatial is contiguous)
  int chunk = blockIdx.y;   // 8 chunks of 8192 floats
  const float4* p = reinterpret_cast<const float4*>(x + (size_t)bg * 65536 + (size_t)chunk * 8192);
  int tid = threadIdx.x;
  float s = 0.f, sq = 0.f;
#pragma unroll
  for (int i = 0; i < 8; ++i) {
    float4 v = p[i * 256 + tid];
    s  += v.x + v.y + v.z + v.w;
    sq += v.x*v.x + v.y*v.y + v.z*v.z + v.w*v.w;
  }
  for (int off = 32; off; off >>= 1) { s += __shfl_xor(s, off); sq += __shfl_xor(sq, off); }
  __shared__ float red[8];
  int wid = tid >> 6, lane = tid & 63;
  if (lane == 0) { red[wid*2] = s; red[wid*2+1] = sq; }
  __syncthreads();
  if (tid == 0) {
    gnp[(bg*8 + chunk)*2 + 0] = red[0]+red[2]+red[4]+red[6];
    gnp[(bg*8 + chunk)*2 + 1] = red[1]+red[3]+red[5]+red[7];
  }
}

__global__ __launch_bounds__(256) void gn_apply(const float* __restrict__ x,
                                                const float* __restrict__ gw,
                                                const float* __restrict__ gb,
                                                const float* __restrict__ gnp,
                                                float* __restrict__ xn,
                                                u16* __restrict__ xnT) {
  __shared__ float T[64][65];
  int b = blockIdx.x, c0 = blockIdx.y * 64, n0 = blockIdx.z * 64;
  int g = blockIdx.y;  // C/G == 64 == c-tile
  int bg = b * G_ + g;
  float S = 0.f, SQ = 0.f;
#pragma unroll
  for (int i = 0; i < 8; ++i) { S += gnp[(bg*8+i)*2]; SQ += gnp[(bg*8+i)*2+1]; }
  float mean = S * (1.f/65536.f);
  float var  = SQ * (1.f/65536.f) - mean*mean;
  float rstd = rsqrtf(var + EPS);
  int tn = threadIdx.x & 63, tc = threadIdx.x >> 6;
#pragma unroll 4
  for (int it = 0; it < 16; ++it) {
    int cl = it*4 + tc;
    int c = c0 + cl;
    size_t idx = ((size_t)b*C_ + c)*N_ + n0 + tn;
    float v = x[idx];
    float r = (v - mean) * rstd * gw[c] + gb[c];
    xn[idx] = r;
    T[tn][cl] = r;
  }
  __syncthreads();
#pragma unroll 4
  for (int it = 0; it < 16; ++it) {
    int nl = it*4 + tc;
    xnT[((size_t)(b*N_ + n0 + nl))*C_ + c0 + tn] = f2b(T[nl][tn]);
  }
}

// ---------------- weight fp32 -> bf16 ----------------
__global__ __launch_bounds__(256) void cvt_w(const float* __restrict__ w,
                                             u16* __restrict__ o, int n4) {
  int i = blockIdx.x * 256 + threadIdx.x;
  if (i < n4) {
    float4 v = reinterpret_cast<const float4*>(w)[i];
    u16x4 r = { f2b(v.x), f2b(v.y), f2b(v.z), f2b(v.w) };
    reinterpret_cast<u16x4*>(o)[i] = r;
  }
}

// ---------------- GEMM ----------------
// TA==0: A[m,k] at Ab[m*lda + k] (K-contig)      TA==1: A[m,k] at Ab[k*lda + m] (M-contig)
// TB==1: B[k,n] at Bp[n*ldb + k] (K-contig, B^T) TB==0: B[k,n] at Bp[k*ldb + n] (N-contig)
// EPI 0: qkv split (O0=q f32, O1=k bf16, O2=v bf16, +bias)
// EPI 1: bf16 out O0 with batch strideC
// EPI 3: f32 out O0 + bias
template<int TA, int TB, int EPI>
__global__ __launch_bounds__(256) void gemm(const u16* __restrict__ A,
                                            const u16* __restrict__ Bm,
                                            int M, int N, int K, int lda, int ldb,
                                            long strideA, long strideB, long strideC,
                                            const float* __restrict__ bias,
                                            void* __restrict__ O0, void* __restrict__ O1,
                                            void* __restrict__ O2) {
  constexpr int BM = 128, BN = 128, BK = 64;
  __shared__ u16 As[BM*BK];
  __shared__ u16 Bs[BN*BK];
  int tid = threadIdx.x, wid = tid >> 6, lane = tid & 63;
  int m0 = blockIdx.x * BM, n0 = blockIdx.y * BN;
  const u16* Ab = A + (size_t)strideA * blockIdx.z;
  const u16* Bp = Bm + (size_t)strideB * blockIdx.z;

  f32x4 acc[4][4] = {};
  int wm = (wid >> 1) * 64, wn = (wid & 1) * 64;

  for (int k0 = 0; k0 < K; k0 += BK) {
    if constexpr (TA == 0) {
#pragma unroll
      for (int t = 0; t < 4; ++t) {
        int chunk = wid*4 + t;
        const u16* src = Ab + (size_t)(m0 + chunk*8 + (lane>>3))*lda + k0 + (lane&7)*8;
        gl2lds16(src, (void*)(As + chunk*512));
      }
    } else {
#pragma unroll
      for (int t = 0; t < 4; ++t) {
        int chunk = wid*4 + t;
        const u16* src = Ab + (size_t)(k0 + chunk*4 + (lane>>4))*lda + m0 + (lane&15)*8;
        gl2lds16(src, (void*)(As + chunk*512));
      }
    }
    if constexpr (TB == 1) {
#pragma unroll
      for (int t = 0; t < 4; ++t) {
        int chunk = wid*4 + t;
        const u16* src = Bp + (size_t)(n0 + chunk*8 + (lane>>3))*ldb + k0 + (lane&7)*8;
        gl2lds16(src, (void*)(Bs + chunk*512));
      }
    } else {
#pragma unroll
      for (int t = 0; t < 4; ++t) {
        int chunk = wid*4 + t;
        const u16* src = Bp + (size_t)(k0 + chunk*4 + (lane>>4))*ldb + n0 + (lane&15)*8;
        gl2lds16(src, (void*)(Bs + chunk*512));
      }
    }
    __syncthreads();

#pragma unroll
    for (int ks = 0; ks < BK; ks += 32) {
      s16x8 af[4], bfr[4];
#pragma unroll
      for (int mi = 0; mi < 4; ++mi) {
        if constexpr (TA == 0) {
          af[mi] = *reinterpret_cast<const s16x8*>(As + (wm + mi*16 + (lane&15))*BK + ks + (lane>>4)*8);
        } else {
          int m = wm + mi*16 + (lane&15);
          int kb = ks + (lane>>4)*8;
#pragma unroll
          for (int j = 0; j < 8; ++j) af[mi][j] = (short)As[(kb + j)*BM + m];
        }
      }
#pragma unroll
      for (int ni = 0; ni < 4; ++ni) {
        if constexpr (TB == 1) {
          bfr[ni] = *reinterpret_cast<const s16x8*>(Bs + (wn + ni*16 + (lane&15))*BK + ks + (lane>>4)*8);
        } else {
          int n = wn + ni*16 + (lane&15);
          int kb = ks + (lane>>4)*8;
#pragma unroll
          for (int j = 0; j < 8; ++j) bfr[ni][j] = (short)Bs[(kb + j)*BN + n];
        }
      }
#pragma unroll
      for (int mi = 0; mi < 4; ++mi)
#pragma unroll
        for (int ni = 0; ni < 4; ++ni)
          acc[mi][ni] = __builtin_amdgcn_mfma_f32_16x16x32_bf16(af[mi], bfr[ni], acc[mi][ni], 0, 0, 0);
    }
    __syncthreads();
  }

#pragma unroll
  for (int mi = 0; mi < 4; ++mi) {
#pragma unroll
    for (int ni = 0; ni < 4; ++ni) {
#pragma unroll
      for (int r = 0; r < 4; ++r) {
        int row = m0 + wm + mi*16 + (lane>>4)*4 + r;
        int col = n0 + wn + ni*16 + (lane&15);
        float v = acc[mi][ni][r];
        if constexpr (EPI == 0) {
          v += bias[col];
          if (col < 512)       ((float*)O0)[(size_t)row*512 + col]        = v;
          else if (col < 1024) ((u16*)O1)[(size_t)row*512 + col - 512]    = f2b(v);
          else                 ((u16*)O2)[(size_t)row*512 + col - 1024]   = f2b(v);
        } else if constexpr (EPI == 1) {
          ((u16*)O0)[(size_t)strideC*blockIdx.z + (size_t)row*N + col] = f2b(v);
        } else {
          ((float*)O0)[(size_t)row*N + col] = v + bias[col];
        }
      }
    }
  }
}

// ---------------- k softmax (rows of 512, in place) ----------------
__global__ __launch_bounds__(256) void k_softmax(u16* __restrict__ k) {
  int wid = threadIdx.x >> 6, lane = threadIdx.x & 63;
  size_t row = (size_t)blockIdx.x * 4 + wid;
  u16* p = k + row * 512;
  s16x8 raw = reinterpret_cast<const s16x8*>(p)[lane];
  float v[8]; float m = -3e38f;
#pragma unroll
  for (int j = 0; j < 8; ++j) { v[j] = b2f((u16)raw[j]); m = fmaxf(m, v[j]); }
  for (int off = 32; off; off >>= 1) m = fmaxf(m, __shfl_xor(m, off));
  float s = 0.f;
#pragma unroll
  for (int j = 0; j < 8; ++j) { v[j] = __expf(v[j] - m); s += v[j]; }
  for (int off = 32; off; off >>= 1) s += __shfl_xor(s, off);
  float inv = 1.f / s;
  s16x8 o;
#pragma unroll
  for (int j = 0; j < 8; ++j) o[j] = (short)f2b(v[j] * inv);
  reinterpret_cast<s16x8*>(p)[lane] = o;
}

// ---------------- q softmax over tokens (columns), split over N ----------------
__global__ __launch_bounds__(256) void q_part(const float* __restrict__ q,
                                              float* __restrict__ qms) {
  int b = blockIdx.x, c = blockIdx.y*256 + threadIdx.x, sp = blockIdx.z;
  const float* col = q + (size_t)b*N_*C_ + c;
  float m = -3e38f, s = 0.f;
#pragma unroll 8
  for (int i = 0; i < 128; ++i) {
    float v = col[(size_t)(sp*128 + i)*C_];
    float nm = fmaxf(m, v);
    s = s*__expf(m - nm) + __expf(v - nm);
    m = nm;
  }
  size_t o = ((size_t)(b*C_ + c)*8 + sp)*2;
  qms[o] = m; qms[o+1] = s;
}

__global__ __launch_bounds__(256) void q_apply(const float* __restrict__ q,
                                               const float* __restrict__ qms,
                                               u16* __restrict__ qs) {
  int b = blockIdx.x, c = blockIdx.y*256 + threadIdx.x, sp = blockIdx.z;
  const float* pm = qms + (size_t)(b*C_ + c)*16;
  float M = -3e38f;
#pragma unroll
  for (int i = 0; i < 8; ++i) M = fmaxf(M, pm[i*2]);
  float S = 0.f;
#pragma unroll
  for (int i = 0; i < 8; ++i) S += pm[i*2+1] * __expf(pm[i*2] - M);
  float inv = 1.f / S;
  const float* col = q + (size_t)b*N_*C_ + c;
  u16* ocol = qs + (size_t)b*N_*C_ + c;
#pragma unroll 8
  for (int i = 0; i < 128; ++i) {
    size_t n = (size_t)(sp*128 + i)*C_;
    ocol[n] = f2b(__expf(col[n] - M) * inv);
  }
}

// ---------------- final transpose + residual ----------------
__global__ __launch_bounds__(256) void final_tr(const float* __restrict__ o2,
                                                const float* __restrict__ xn,
                                                float* __restrict__ out) {
  __shared__ float T[64][65];
  int b = blockIdx.x, c0 = blockIdx.y*64, n0 = blockIdx.z*64;
  int t0 = threadIdx.x & 63, t1 = threadIdx.x >> 6;
#pragma unroll 4
  for (int it = 0; it < 16; ++it) {
    int nl = it*4 + t1;
    T[t0][nl] = o2[((size_t)(b*N_ + n0 + nl))*C_ + c0 + t0];
  }
  __syncthreads();
#pragma unroll 4
  for (int it = 0; it < 16; ++it) {
    int cl = it*4 + t1;
    size_t idx = ((size_t)(b*C_ + c0 + cl))*N_ + n0 + t0;
    out[idx] = T[cl][t0] + xn[idx];
  }
}

// ---------------- launch ----------------
extern "C" void kernel_launch(void* const* d_in, const int* in_sizes, int n_in,
                              void* d_out, int out_size, void* d_ws, size_t ws_size,
                              hipStream_t stream) {
  (void)in_sizes; (void)n_in; (void)out_size; (void)ws_size;
  const float* x      = (const float*)d_in[0];
  const float* gn_w   = (const float*)d_in[1];
  const float* gn_b   = (const float*)d_in[2];
  const float* qkv_w  = (const float*)d_in[3];
  const float* qkv_b  = (const float*)d_in[4];
  const float* proj_w = (const float*)d_in[5];
  const float* proj_b = (const float*)d_in[6];

  char* ws = (char*)d_ws;
  float* xn  = (float*)(ws + OFF_XN);
  u16*   xnT = (u16*)  (ws + OFF_XNT);
  float* qf  = (float*)(ws + OFF_QF);     // q fp32, later reused as out2 fp32
  u16*   kb  = (u16*)  (ws + OFF_K);
  u16*   vb  = (u16*)  (ws + OFF_V);
  u16*   qsb = (u16*)  (ws + OFF_QS);
  u16*   ctx = (u16*)  (ws + OFF_CTX);
  u16*   att = (u16*)  (ws + OFF_ATT);
  u16*   wq  = (u16*)  (ws + OFF_WQ);
  u16*   wp  = (u16*)  (ws + OFF_WP);
  float* gnp = (float*)(ws + OFF_GNP);
  float* qms = (float*)(ws + OFF_QMS);

  gn_partial<<<dim3(64, 8), 256, 0, stream>>>(x, gnp);
  gn_apply<<<dim3(8, 8, 16), 256, 0, stream>>>(x, gn_w, gn_b, gnp, xn, xnT);

  cvt_w<<<dim3(768), 256, 0, stream>>>(qkv_w, wq, 1536*512/4);
  cvt_w<<<dim3(256), 256, 0, stream>>>(proj_w, wp, 512*512/4);

  // qkv: [8192,512] x [1536,512]^T -> q f32 / k bf16 / v bf16
  gemm<0,1,0><<<dim3(64, 12, 1), 256, 0, stream>>>(xnT, wq, 8192, 1536, 512, 512, 512,
                                                   0, 0, 0, qkv_b, qf, kb, vb);
  k_softmax<<<dim3(2048), 256, 0, stream>>>(kb);
  q_part<<<dim3(8, 2, 8), 256, 0, stream>>>(qf, qms);
  q_apply<<<dim3(8, 2, 8), 256, 0, stream>>>(qf, qms, qsb);

  // ctx[b,c,d] = sum_n k[b,n,c] v[b,n,d]  (A M-contig, B N-contig)
  gemm<1,0,1><<<dim3(4, 4, 8), 256, 0, stream>>>(kb, vb, 512, 512, 1024, 512, 512,
                                                 524288, 524288, 262144, nullptr, ctx, nullptr, nullptr);
  // att[b,n,d] = sum_c q_s[b,n,c] ctx[b,c,d]
  gemm<0,0,1><<<dim3(8, 4, 8), 256, 0, stream>>>(qsb, ctx, 1024, 512, 512, 512, 512,
                                                 524288, 262144, 524288, nullptr, att, nullptr, nullptr);
  // proj: [8192,512] x [512,512]^T + bias -> out2 f32 (reuse qf)
  gemm<0,1,3><<<dim3(64, 4, 1), 256, 0, stream>>>(att, wp, 8192, 512, 512, 512, 512,
                                                  0, 0, 0, proj_b, qf, nullptr, nullptr);

  final_tr<<<dim3(8, 8, 16), 256, 0, stream>>>(qf, xn, (float*)d_out);
}

// Round 2
// 207.843 us; speedup vs baseline: 1.0431x; 1.0431x over previous
//
#include <hip/hip_runtime.h>
#include <hip/hip_bf16.h>
#include <stdint.h>

typedef unsigned short u16;
typedef __attribute__((ext_vector_type(8))) short s16x8;
typedef __attribute__((ext_vector_type(4))) float f32x4;
typedef __attribute__((ext_vector_type(4))) unsigned short u16x4;

static constexpr int B_ = 8, C_ = 512, N_ = 1024, G_ = 8;
static constexpr float EPS = 1e-5f;

// ---------------- workspace layout (bytes) ----------------
static constexpr size_t OFF_XN   = 0;         // f32 [B][C][N]   16 MB (residual)
static constexpr size_t OFF_XNT  = 16777216;  // bf16 [B][N][C]   8 MB (GEMM A)
static constexpr size_t OFF_QF   = 25165824;  // f32 [B][N][C]   16 MB (q pre-softmax)
static constexpr size_t OFF_K    = 41943040;  // bf16 [B][N][C]   8 MB (k raw)
static constexpr size_t OFF_VT   = 50331648;  // bf16 [B][C][N]   8 MB (v transposed)
static constexpr size_t OFF_KT   = 58720256;  // bf16 [B][C][N]   8 MB (softmax(k) transposed)
static constexpr size_t OFF_QS   = 67108864;  // bf16 [B][N][C]   8 MB (q post-softmax)
static constexpr size_t OFF_CTXT = 75497472;  // bf16 [B][C][C]   4 MB (context^T: [d][c])
static constexpr size_t OFF_ATT  = 79691776;  // bf16 [B][N][C]   8 MB
static constexpr size_t OFF_WQ   = 88080384;  // bf16 [1536][512] 1.5 MB
static constexpr size_t OFF_WP   = 89653248;  // bf16 [512][512]  0.5 MB
static constexpr size_t OFF_GNP  = 90177536;  // f32 [64][8][2]   4 KB
static constexpr size_t OFF_QMS  = 90181632;  // f32 [B][C][8][2] 256 KB

// ---------------- helpers ----------------
__device__ __forceinline__ float b2f(u16 u) {
  union { float f; uint32_t i; } x; x.i = ((uint32_t)u) << 16; return x.f;
}
__device__ __forceinline__ u16 f2b(float f) {
  union { float f; uint32_t i; } x; x.f = f;
  return (u16)((x.i + 0x7fffu + ((x.i >> 16) & 1u)) >> 16);
}
#define AS1 __attribute__((address_space(1)))
#define AS3 __attribute__((address_space(3)))
__device__ __forceinline__ void gl2lds16(const void* g, void* l) {
  __builtin_amdgcn_global_load_lds((const AS1 void*)g, (AS3 void*)l, 16, 0, 0);
}

// ---------------- groupnorm ----------------
__global__ __launch_bounds__(256) void gn_partial(const float* __restrict__ x,
                                                  float* __restrict__ gnp) {
  int bg = blockIdx.x;      // 64 = B*G (group = 64ch x 1024 spatial, contiguous)
  int chunk = blockIdx.y;   // 8 chunks of 8192 floats
  const float4* p = reinterpret_cast<const float4*>(x + (size_t)bg * 65536 + (size_t)chunk * 8192);
  int tid = threadIdx.x;
  float s = 0.f, sq = 0.f;
#pragma unroll
  for (int i = 0; i < 8; ++i) {
    float4 v = p[i * 256 + tid];
    s  += v.x + v.y + v.z + v.w;
    sq += v.x*v.x + v.y*v.y + v.z*v.z + v.w*v.w;
  }
  for (int off = 32; off; off >>= 1) { s += __shfl_xor(s, off); sq += __shfl_xor(sq, off); }
  __shared__ float red[8];
  int wid = tid >> 6, lane = tid & 63;
  if (lane == 0) { red[wid*2] = s; red[wid*2+1] = sq; }
  __syncthreads();
  if (tid == 0) {
    gnp[(bg*8 + chunk)*2 + 0] = red[0]+red[2]+red[4]+red[6];
    gnp[(bg*8 + chunk)*2 + 1] = red[1]+red[3]+red[5]+red[7];
  }
}

__global__ __launch_bounds__(256) void gn_apply(const float* __restrict__ x,
                                                const float* __restrict__ gw,
                                                const float* __restrict__ gb,
                                                const float* __restrict__ gnp,
                                                float* __restrict__ xn,
                                                u16* __restrict__ xnT) {
  __shared__ float T[64][65];
  int b = blockIdx.x, c0 = blockIdx.y * 64, n0 = blockIdx.z * 64;
  int g = blockIdx.y;  // C/G == 64 == c-tile
  int bg = b * G_ + g;
  float S = 0.f, SQ = 0.f;
#pragma unroll
  for (int i = 0; i < 8; ++i) { S += gnp[(bg*8+i)*2]; SQ += gnp[(bg*8+i)*2+1]; }
  float mean = S * (1.f/65536.f);
  float var  = SQ * (1.f/65536.f) - mean*mean;
  float rstd = rsqrtf(var + EPS);
  int tn = threadIdx.x & 63, tc = threadIdx.x >> 6;
#pragma unroll 4
  for (int it = 0; it < 16; ++it) {
    int cl = it*4 + tc;
    int c = c0 + cl;
    size_t idx = ((size_t)b*C_ + c)*N_ + n0 + tn;
    float v = x[idx];
    float r = (v - mean) * rstd * gw[c] + gb[c];
    xn[idx] = r;
    T[tn][cl] = r;
  }
  __syncthreads();
#pragma unroll 4
  for (int it = 0; it < 16; ++it) {
    int nl = it*4 + tc;
    xnT[((size_t)(b*N_ + n0 + nl))*C_ + c0 + tn] = f2b(T[nl][tn]);
  }
}

// ---------------- weight fp32 -> bf16 ----------------
__global__ __launch_bounds__(256) void cvt_w(const float* __restrict__ w,
                                             u16* __restrict__ o, int n4) {
  int i = blockIdx.x * 256 + threadIdx.x;
  if (i < n4) {
    float4 v = reinterpret_cast<const float4*>(w)[i];
    u16x4 r = { f2b(v.x), f2b(v.y), f2b(v.z), f2b(v.w) };
    reinterpret_cast<u16x4*>(o)[i] = r;
  }
}

// ---------------- GEMM (A K-contig, B given as B^T K-contig) ----------------
// O[m,col] = sum_k A[m*lda+k] * B[col*ldb+k]  (+ epilogue)
// EPI 0: qkv split (O0=q f32, O1=k bf16 [n][c], O2=v bf16 TRANSPOSED [b][d][n]; +bias)
// EPI 1: bf16 out O0, batch strideC, layout [row][col]
// EPI 2: proj: f32 out to O0 in [b][col][n] layout, + bias + residual from O1 (xn)
template<int EPI>
__global__ __launch_bounds__(256) void gemm(const u16* __restrict__ A,
                                            const u16* __restrict__ Bm,
                                            int M, int N, int K, int lda, int ldb,
                                            long strideA, long strideB, long strideC,
                                            const float* __restrict__ bias,
                                            void* __restrict__ O0,
                                            const void* __restrict__ O1) {
  constexpr int BM = 128, BN = 128, BK = 64;
  __shared__ u16 As[BM*BK];
  __shared__ u16 Bs[BN*BK];
  int tid = threadIdx.x, wid = tid >> 6, lane = tid & 63;
  int m0 = blockIdx.x * BM, n0 = blockIdx.y * BN;
  const u16* Ab = A + (size_t)strideA * blockIdx.z;
  const u16* Bp = Bm + (size_t)strideB * blockIdx.z;

  f32x4 acc[4][4] = {};
  int wm = (wid >> 1) * 64, wn = (wid & 1) * 64;

  for (int k0 = 0; k0 < K; k0 += BK) {
#pragma unroll
    for (int t = 0; t < 4; ++t) {
      int chunk = wid*4 + t;
      const u16* srcA = Ab + (size_t)(m0 + chunk*8 + (lane>>3))*lda + k0 + (lane&7)*8;
      gl2lds16(srcA, (void*)(As + chunk*512));
    }
#pragma unroll
    for (int t = 0; t < 4; ++t) {
      int chunk = wid*4 + t;
      const u16* srcB = Bp + (size_t)(n0 + chunk*8 + (lane>>3))*ldb + k0 + (lane&7)*8;
      gl2lds16(srcB, (void*)(Bs + chunk*512));
    }
    __syncthreads();

#pragma unroll
    for (int ks = 0; ks < BK; ks += 32) {
      s16x8 af[4], bfr[4];
#pragma unroll
      for (int mi = 0; mi < 4; ++mi)
        af[mi] = *reinterpret_cast<const s16x8*>(As + (wm + mi*16 + (lane&15))*BK + ks + (lane>>4)*8);
#pragma unroll
      for (int ni = 0; ni < 4; ++ni)
        bfr[ni] = *reinterpret_cast<const s16x8*>(Bs + (wn + ni*16 + (lane&15))*BK + ks + (lane>>4)*8);
#pragma unroll
      for (int mi = 0; mi < 4; ++mi)
#pragma unroll
        for (int ni = 0; ni < 4; ++ni)
          acc[mi][ni] = __builtin_amdgcn_mfma_f32_16x16x32_bf16(af[mi], bfr[ni], acc[mi][ni], 0, 0, 0);
    }
    __syncthreads();
  }

#pragma unroll
  for (int mi = 0; mi < 4; ++mi) {
#pragma unroll
    for (int ni = 0; ni < 4; ++ni) {
      int col = n0 + wn + ni*16 + (lane&15);
      if constexpr (EPI == 2) {
        // rows = 4 consecutive tokens at one output channel -> contiguous in [b][c][n]
        int rowb = m0 + wm + mi*16 + (lane>>4)*4;
        int b = rowb >> 10, n = rowb & 1023;
        size_t idx = (size_t)b*524288 + (size_t)col*1024 + n;
        float4 xr = *reinterpret_cast<const float4*>((const float*)O1 + idx);
        float bi = bias[col];
        float4 o;
        o.x = acc[mi][ni][0] + bi + xr.x;
        o.y = acc[mi][ni][1] + bi + xr.y;
        o.z = acc[mi][ni][2] + bi + xr.z;
        o.w = acc[mi][ni][3] + bi + xr.w;
        *reinterpret_cast<float4*>((float*)O0 + idx) = o;
      } else {
#pragma unroll
        for (int r = 0; r < 4; ++r) {
          int row = m0 + wm + mi*16 + (lane>>4)*4 + r;
          float v = acc[mi][ni][r];
          if constexpr (EPI == 0) {
            v += bias[col];
            char* o0 = (char*)O0;
            if (col < 512) {
              ((float*)o0)[(size_t)row*512 + col] = v;                       // q f32 [n][c]
            } else if (col < 1024) {
              (((u16*)o0) + (OFF_K - OFF_QF)/2*0)[0] = 0; // (never taken path placeholder removed below)
            }
          } else if constexpr (EPI == 1) {
            ((u16*)O0)[(size_t)strideC*blockIdx.z + (size_t)row*N + col] = f2b(v);
          }
        }
      }
    }
  }
}

// Specialized qkv epilogue GEMM (EPI 0 needs three outputs; separate kernel to keep
// the template signature clean).
__global__ __launch_bounds__(256) void gemm_qkv(const u16* __restrict__ A,
                                                const u16* __restrict__ Bm,
                                                const float* __restrict__ bias,
                                                float* __restrict__ Oq,
                                                u16* __restrict__ Ok,
                                                u16* __restrict__ OvT) {
  constexpr int BM = 128, BN = 128, BK = 64;
  const int lda = 512, ldb = 512, K = 512;
  __shared__ u16 As[BM*BK];
  __shared__ u16 Bs[BN*BK];
  int tid = threadIdx.x, wid = tid >> 6, lane = tid & 63;
  int m0 = blockIdx.x * BM, n0 = blockIdx.y * BN;

  f32x4 acc[4][4] = {};
  int wm = (wid >> 1) * 64, wn = (wid & 1) * 64;

  for (int k0 = 0; k0 < K; k0 += BK) {
#pragma unroll
    for (int t = 0; t < 4; ++t) {
      int chunk = wid*4 + t;
      gl2lds16(A + (size_t)(m0 + chunk*8 + (lane>>3))*lda + k0 + (lane&7)*8,
               (void*)(As + chunk*512));
    }
#pragma unroll
    for (int t = 0; t < 4; ++t) {
      int chunk = wid*4 + t;
      gl2lds16(Bm + (size_t)(n0 + chunk*8 + (lane>>3))*ldb + k0 + (lane&7)*8,
               (void*)(Bs + chunk*512));
    }
    __syncthreads();
#pragma unroll
    for (int ks = 0; ks < BK; ks += 32) {
      s16x8 af[4], bfr[4];
#pragma unroll
      for (int mi = 0; mi < 4; ++mi)
        af[mi] = *reinterpret_cast<const s16x8*>(As + (wm + mi*16 + (lane&15))*BK + ks + (lane>>4)*8);
#pragma unroll
      for (int ni = 0; ni < 4; ++ni)
        bfr[ni] = *reinterpret_cast<const s16x8*>(Bs + (wn + ni*16 + (lane&15))*BK + ks + (lane>>4)*8);
#pragma unroll
      for (int mi = 0; mi < 4; ++mi)
#pragma unroll
        for (int ni = 0; ni < 4; ++ni)
          acc[mi][ni] = __builtin_amdgcn_mfma_f32_16x16x32_bf16(af[mi], bfr[ni], acc[mi][ni], 0, 0, 0);
    }
    __syncthreads();
  }

#pragma unroll
  for (int mi = 0; mi < 4; ++mi) {
#pragma unroll
    for (int ni = 0; ni < 4; ++ni) {
      int col = n0 + wn + ni*16 + (lane&15);
      float bi = bias[col];
#pragma unroll
      for (int r = 0; r < 4; ++r) {
        int row = m0 + wm + mi*16 + (lane>>4)*4 + r;
        float v = acc[mi][ni][r] + bi;
        if (col < 512) {
          Oq[(size_t)row*512 + col] = v;                                    // q f32 [tok][c]
        } else if (col < 1024) {
          Ok[(size_t)row*512 + (col - 512)] = f2b(v);                       // k bf16 [tok][c]
        } else {
          int d = col - 1024;                                               // vT bf16 [b][d][n]
          OvT[((size_t)(row >> 10))*524288 + (size_t)d*1024 + (row & 1023)] = f2b(v);
        }
      }
    }
  }
}

// ---------------- k row-softmax + transpose: k[b][n][c] -> kT[b][c][n] ----------------
__global__ __launch_bounds__(256) void k_softmax_t(const u16* __restrict__ k,
                                                   u16* __restrict__ kT) {
  __shared__ u16 T[32][516];   // +4 u16 pad: row stride 258 words -> 2-way max (free)
  int b = blockIdx.x, n0 = blockIdx.y * 32;
  int wid = threadIdx.x >> 6, lane = threadIdx.x & 63;
#pragma unroll
  for (int i = 0; i < 8; ++i) {
    int r = wid * 8 + i;
    const u16* p = k + ((size_t)(b*N_ + n0 + r))*C_;
    s16x8 raw = reinterpret_cast<const s16x8*>(p)[lane];
    float v[8]; float m = -3e38f;
#pragma unroll
    for (int j = 0; j < 8; ++j) { v[j] = b2f((u16)raw[j]); m = fmaxf(m, v[j]); }
    for (int off = 32; off; off >>= 1) m = fmaxf(m, __shfl_xor(m, off));
    float s = 0.f;
#pragma unroll
    for (int j = 0; j < 8; ++j) { v[j] = __expf(v[j] - m); s += v[j]; }
    for (int off = 32; off; off >>= 1) s += __shfl_xor(s, off);
    float inv = 1.f / s;
    union { s16x8 v8; unsigned long long d[2]; } o;
#pragma unroll
    for (int j = 0; j < 8; ++j) o.v8[j] = (short)f2b(v[j] * inv);
    unsigned long long* dst = reinterpret_cast<unsigned long long*>(&T[r][lane*8]);
    dst[0] = o.d[0]; dst[1] = o.d[1];
  }
  __syncthreads();
#pragma unroll
  for (int h = 0; h < 2; ++h) {
    int c = h*256 + threadIdx.x;
    u16* dst = kT + ((size_t)(b*C_ + c))*N_ + n0;
#pragma unroll
    for (int q4 = 0; q4 < 4; ++q4) {
      s16x8 o;
#pragma unroll
      for (int j = 0; j < 8; ++j) o[j] = (short)T[q4*8 + j][c];
      reinterpret_cast<s16x8*>(dst)[q4] = o;
    }
  }
}

// ---------------- q softmax over tokens (columns), split over N ----------------
__global__ __launch_bounds__(256) void q_part(const float* __restrict__ q,
                                              float* __restrict__ qms) {
  int b = blockIdx.x, c = blockIdx.y*256 + threadIdx.x, sp = blockIdx.z;
  const float* col = q + (size_t)b*N_*C_ + c;
  float m = -3e38f, s = 0.f;
#pragma unroll 8
  for (int i = 0; i < 128; ++i) {
    float v = col[(size_t)(sp*128 + i)*C_];
    float nm = fmaxf(m, v);
    s = s*__expf(m - nm) + __expf(v - nm);
    m = nm;
  }
  size_t o = ((size_t)(b*C_ + c)*8 + sp)*2;
  qms[o] = m; qms[o+1] = s;
}

__global__ __launch_bounds__(256) void q_apply(const float* __restrict__ q,
                                               const float* __restrict__ qms,
                                               u16* __restrict__ qs) {
  int b = blockIdx.x, c = blockIdx.y*256 + threadIdx.x, sp = blockIdx.z;
  const float* pm = qms + (size_t)(b*C_ + c)*16;
  float M = -3e38f;
#pragma unroll
  for (int i = 0; i < 8; ++i) M = fmaxf(M, pm[i*2]);
  float S = 0.f;
#pragma unroll
  for (int i = 0; i < 8; ++i) S += pm[i*2+1] * __expf(pm[i*2] - M);
  float inv = 1.f / S;
  const float* col = q + (size_t)b*N_*C_ + c;
  u16* ocol = qs + (size_t)b*N_*C_ + c;
#pragma unroll 8
  for (int i = 0; i < 128; ++i) {
    size_t n = (size_t)(sp*128 + i)*C_;
    ocol[n] = f2b(__expf(col[n] - M) * inv);
  }
}

// ---------------- launch ----------------
extern "C" void kernel_launch(void* const* d_in, const int* in_sizes, int n_in,
                              void* d_out, int out_size, void* d_ws, size_t ws_size,
                              hipStream_t stream) {
  (void)in_sizes; (void)n_in; (void)out_size; (void)ws_size;
  const float* x      = (const float*)d_in[0];
  const float* gn_w   = (const float*)d_in[1];
  const float* gn_b   = (const float*)d_in[2];
  const float* qkv_w  = (const float*)d_in[3];
  const float* qkv_b  = (const float*)d_in[4];
  const float* proj_w = (const float*)d_in[5];
  const float* proj_b = (const float*)d_in[6];

  char* ws = (char*)d_ws;
  float* xn   = (float*)(ws + OFF_XN);
  u16*   xnT  = (u16*)  (ws + OFF_XNT);
  float* qf   = (float*)(ws + OFF_QF);
  u16*   kb   = (u16*)  (ws + OFF_K);
  u16*   vT   = (u16*)  (ws + OFF_VT);
  u16*   kT   = (u16*)  (ws + OFF_KT);
  u16*   qsb  = (u16*)  (ws + OFF_QS);
  u16*   ctxT = (u16*)  (ws + OFF_CTXT);
  u16*   att  = (u16*)  (ws + OFF_ATT);
  u16*   wq   = (u16*)  (ws + OFF_WQ);
  u16*   wp   = (u16*)  (ws + OFF_WP);
  float* gnp  = (float*)(ws + OFF_GNP);
  float* qms  = (float*)(ws + OFF_QMS);

  gn_partial<<<dim3(64, 8), 256, 0, stream>>>(x, gnp);
  gn_apply<<<dim3(8, 8, 16), 256, 0, stream>>>(x, gn_w, gn_b, gnp, xn, xnT);

  cvt_w<<<dim3(768), 256, 0, stream>>>(qkv_w, wq, 1536*512/4);
  cvt_w<<<dim3(256), 256, 0, stream>>>(proj_w, wp, 512*512/4);

  // qkv: [8192,512] x [1536,512]^T -> q f32 [tok][c], k bf16 [tok][c], vT bf16 [b][d][n]
  gemm_qkv<<<dim3(64, 12, 1), 256, 0, stream>>>(xnT, wq, qkv_b, qf, kb, vT);

  k_softmax_t<<<dim3(8, 32), 256, 0, stream>>>(kb, kT);
  q_part<<<dim3(8, 2, 8), 256, 0, stream>>>(qf, qms);
  q_apply<<<dim3(8, 2, 8), 256, 0, stream>>>(qf, qms, qsb);

  // ctxT[b][d][c] = sum_n vT[b][d][n] * kT[b][c][n]   (both K-contig)
  gemm<1><<<dim3(4, 4, 8), 256, 0, stream>>>(vT, kT, 512, 512, 1024, 1024, 1024,
                                             524288, 524288, 262144, nullptr, ctxT, nullptr);
  // att[b][n][d] = sum_c qs[b][n][c] * ctxT[b][d][c]  (both K-contig)
  gemm<1><<<dim3(8, 4, 8), 256, 0, stream>>>(qsb, ctxT, 1024, 512, 512, 512, 512,
                                             524288, 262144, 524288, nullptr, att, nullptr);
  // proj + bias + residual + transpose: out[b][c][n] = att[tok]·wp^T + proj_b + xn
  gemm<2><<<dim3(64, 4, 1), 256, 0, stream>>>(att, wp, 8192, 512, 512, 512, 512,
                                              0, 0, 0, proj_b, (float*)d_out, xn);
}

// Round 3
// 202.842 us; speedup vs baseline: 1.0688x; 1.0247x over previous
//
#include <hip/hip_runtime.h>
#include <hip/hip_bf16.h>
#include <stdint.h>

typedef unsigned short u16;
typedef __attribute__((ext_vector_type(8))) short s16x8;
typedef __attribute__((ext_vector_type(4))) float f32x4;
typedef __attribute__((ext_vector_type(4))) unsigned short u16x4;

static constexpr int B_ = 8, C_ = 512, N_ = 1024, G_ = 8;
static constexpr float EPS = 1e-5f;

// ---------------- workspace layout (bytes) ----------------
static constexpr size_t OFF_XN   = 0;                                   // f32 [B][C][N] residual
static constexpr size_t OFF_XNT  = OFF_XN   + (size_t)B_*C_*N_*4;       // bf16 [B][N][C]
static constexpr size_t OFF_Q    = OFF_XNT  + (size_t)B_*N_*C_*2;       // bf16 [B][N][C] q raw
static constexpr size_t OFF_K    = OFF_Q    + (size_t)B_*N_*C_*2;       // bf16 [B][N][C] k raw
static constexpr size_t OFF_V    = OFF_K    + (size_t)B_*N_*C_*2;       // bf16 [B][N][C] v raw
static constexpr size_t OFF_KT   = OFF_V    + (size_t)B_*N_*C_*2;       // bf16 [B][C][N] softmax(k)^T
static constexpr size_t OFF_VT   = OFF_KT   + (size_t)B_*N_*C_*2;       // bf16 [B][C][N] v^T
static constexpr size_t OFF_QS   = OFF_VT   + (size_t)B_*N_*C_*2;       // bf16 [B][N][C] softmax(q)
static constexpr size_t OFF_CTXT = OFF_QS   + (size_t)B_*N_*C_*2;       // bf16 [B][C][C] ctx^T [d][c]
static constexpr size_t OFF_ATT  = OFF_CTXT + (size_t)B_*C_*C_*2;       // bf16 [B][N][C]
static constexpr size_t OFF_WQ   = OFF_ATT  + (size_t)B_*N_*C_*2;       // bf16 [1536][512]
static constexpr size_t OFF_WP   = OFF_WQ   + (size_t)3*C_*C_*2;        // bf16 [512][512]
static constexpr size_t OFF_GNP  = OFF_WP   + (size_t)C_*C_*2;          // f32 [64][8][2]
static constexpr size_t OFF_QMS  = OFF_GNP  + 4096;                     // f32 [B][C][8][2]

// ---------------- helpers ----------------
__device__ __forceinline__ float b2f(u16 u) {
  union { float f; uint32_t i; } x; x.i = ((uint32_t)u) << 16; return x.f;
}
__device__ __forceinline__ u16 f2b(float f) {
  union { float f; uint32_t i; } x; x.f = f;
  return (u16)((x.i + 0x7fffu + ((x.i >> 16) & 1u)) >> 16);
}
#define AS1 __attribute__((address_space(1)))
#define AS3 __attribute__((address_space(3)))
__device__ __forceinline__ void gl2lds16(const void* g, void* l) {
  __builtin_amdgcn_global_load_lds((const AS1 void*)g, (AS3 void*)l, 16, 0, 0);
}

// ---------------- groupnorm ----------------
__global__ __launch_bounds__(256) void gn_partial(const float* __restrict__ x,
                                                  float* __restrict__ gnp) {
  int bg = blockIdx.x;      // 64 = B*G
  int chunk = blockIdx.y;   // 8 chunks of 8192 floats
  const float4* p = reinterpret_cast<const float4*>(x + (size_t)bg * 65536 + (size_t)chunk * 8192);
  int tid = threadIdx.x;
  float s = 0.f, sq = 0.f;
#pragma unroll
  for (int i = 0; i < 8; ++i) {
    float4 v = p[i * 256 + tid];
    s  += v.x + v.y + v.z + v.w;
    sq += v.x*v.x + v.y*v.y + v.z*v.z + v.w*v.w;
  }
  for (int off = 32; off; off >>= 1) { s += __shfl_xor(s, off); sq += __shfl_xor(sq, off); }
  __shared__ float red[8];
  int wid = tid >> 6, lane = tid & 63;
  if (lane == 0) { red[wid*2] = s; red[wid*2+1] = sq; }
  __syncthreads();
  if (tid == 0) {
    gnp[(bg*8 + chunk)*2 + 0] = red[0]+red[2]+red[4]+red[6];
    gnp[(bg*8 + chunk)*2 + 1] = red[1]+red[3]+red[5]+red[7];
  }
}

__global__ __launch_bounds__(256) void gn_apply(const float* __restrict__ x,
                                                const float* __restrict__ gw,
                                                const float* __restrict__ gb,
                                                const float* __restrict__ gnp,
                                                float* __restrict__ xn,
                                                u16* __restrict__ xnT) {
  __shared__ float T[64][65];
  int b = blockIdx.x, c0 = blockIdx.y * 64, n0 = blockIdx.z * 64;
  int g = blockIdx.y;
  int bg = b * G_ + g;
  float S = 0.f, SQ = 0.f;
#pragma unroll
  for (int i = 0; i < 8; ++i) { S += gnp[(bg*8+i)*2]; SQ += gnp[(bg*8+i)*2+1]; }
  float mean = S * (1.f/65536.f);
  float var  = SQ * (1.f/65536.f) - mean*mean;
  float rstd = rsqrtf(var + EPS);
  int tn = threadIdx.x & 63, tc = threadIdx.x >> 6;
#pragma unroll 4
  for (int it = 0; it < 16; ++it) {
    int cl = it*4 + tc;
    int c = c0 + cl;
    size_t idx = ((size_t)b*C_ + c)*N_ + n0 + tn;
    float v = x[idx];
    float r = (v - mean) * rstd * gw[c] + gb[c];
    xn[idx] = r;
    T[tn][cl] = r;
  }
  __syncthreads();
#pragma unroll 4
  for (int it = 0; it < 16; ++it) {
    int nl = it*4 + tc;
    xnT[((size_t)(b*N_ + n0 + nl))*C_ + c0 + tn] = f2b(T[nl][tn]);
  }
}

// ---------------- weight fp32 -> bf16 ----------------
__global__ __launch_bounds__(256) void cvt_w(const float* __restrict__ w,
                                             u16* __restrict__ o, int n4) {
  int i = blockIdx.x * 256 + threadIdx.x;
  if (i < n4) {
    float4 v = reinterpret_cast<const float4*>(w)[i];
    u16x4 r = { f2b(v.x), f2b(v.y), f2b(v.z), f2b(v.w) };
    reinterpret_cast<u16x4*>(o)[i] = r;
  }
}

// ---------------- GEMM core (A K-contig, B^T K-contig), double-buffered ----------------
// EPI 1: bf16 out O0 [row][col], ld=N, batch strideC
// EPI 2: proj: f32 out O0 in [b][col][n] layout + bias + residual from R (xn)
template<int EPI>
__global__ __launch_bounds__(256) void gemm(const u16* __restrict__ A,
                                            const u16* __restrict__ Bm,
                                            int M, int N, int K, int lda, int ldb,
                                            long strideA, long strideB, long strideC,
                                            const float* __restrict__ bias,
                                            void* __restrict__ O0,
                                            const void* __restrict__ R) {
  constexpr int BM = 128, BN = 128, BK = 64;
  __shared__ u16 As[2][BM*BK];
  __shared__ u16 Bs[2][BN*BK];
  int tid = threadIdx.x, wid = tid >> 6, lane = tid & 63;
  int m0 = blockIdx.x * BM, n0 = blockIdx.y * BN;
  const u16* Ab = A + (size_t)strideA * blockIdx.z;
  const u16* Bp = Bm + (size_t)strideB * blockIdx.z;

  f32x4 acc[4][4] = {};
  int wm = (wid >> 1) * 64, wn = (wid & 1) * 64;

  auto stage = [&](int buf, int k0) {
#pragma unroll
    for (int t = 0; t < 4; ++t) {
      int chunk = wid*4 + t;
      gl2lds16(Ab + (size_t)(m0 + chunk*8 + (lane>>3))*lda + k0 + (lane&7)*8,
               (void*)(&As[buf][chunk*512]));
      gl2lds16(Bp + (size_t)(n0 + chunk*8 + (lane>>3))*ldb + k0 + (lane&7)*8,
               (void*)(&Bs[buf][chunk*512]));
    }
  };

  int KT = K / BK;
  stage(0, 0);
  __syncthreads();
  int cur = 0;
  for (int kt = 0; kt < KT; ++kt) {
    if (kt + 1 < KT) stage(cur ^ 1, (kt + 1) * BK);   // prefetch overlaps compute below
#pragma unroll
    for (int ks = 0; ks < BK; ks += 32) {
      s16x8 af[4], bfr[4];
#pragma unroll
      for (int mi = 0; mi < 4; ++mi)
        af[mi] = *reinterpret_cast<const s16x8*>(&As[cur][(wm + mi*16 + (lane&15))*BK + ks + (lane>>4)*8]);
#pragma unroll
      for (int ni = 0; ni < 4; ++ni)
        bfr[ni] = *reinterpret_cast<const s16x8*>(&Bs[cur][(wn + ni*16 + (lane&15))*BK + ks + (lane>>4)*8]);
#pragma unroll
      for (int mi = 0; mi < 4; ++mi)
#pragma unroll
        for (int ni = 0; ni < 4; ++ni)
          acc[mi][ni] = __builtin_amdgcn_mfma_f32_16x16x32_bf16(af[mi], bfr[ni], acc[mi][ni], 0, 0, 0);
    }
    __syncthreads();   // drains prefetch vmcnt (overlapped with MFMA above) + lds reads
    cur ^= 1;
  }

#pragma unroll
  for (int mi = 0; mi < 4; ++mi) {
#pragma unroll
    for (int ni = 0; ni < 4; ++ni) {
      int col = n0 + wn + ni*16 + (lane&15);
      if constexpr (EPI == 2) {
        int rowb = m0 + wm + mi*16 + (lane>>4)*4;
        int b = rowb >> 10, n = rowb & 1023;
        size_t idx = (size_t)b*524288 + (size_t)col*1024 + n;
        float4 xr = *reinterpret_cast<const float4*>((const float*)R + idx);
        float bi = bias[col];
        float4 o;
        o.x = acc[mi][ni][0] + bi + xr.x;
        o.y = acc[mi][ni][1] + bi + xr.y;
        o.z = acc[mi][ni][2] + bi + xr.z;
        o.w = acc[mi][ni][3] + bi + xr.w;
        *reinterpret_cast<float4*>((float*)O0 + idx) = o;
      } else {
#pragma unroll
        for (int r = 0; r < 4; ++r) {
          int row = m0 + wm + mi*16 + (lane>>4)*4 + r;
          ((u16*)O0)[(size_t)strideC*blockIdx.z + (size_t)row*N + col] = f2b(acc[mi][ni][r]);
        }
      }
    }
  }
}

// ---------------- qkv GEMM: A=xnT[8192][512], B=wq[1536][512]; q,k,v coalesced bf16 [tok][c]
__global__ __launch_bounds__(256) void gemm_qkv(const u16* __restrict__ A,
                                                const u16* __restrict__ Bm,
                                                const float* __restrict__ bias,
                                                u16* __restrict__ Oq,
                                                u16* __restrict__ Ok,
                                                u16* __restrict__ Ov) {
  constexpr int BM = 128, BN = 128, BK = 64;
  const int lda = 512, ldb = 512, K = 512;
  __shared__ u16 As[2][BM*BK];
  __shared__ u16 Bs[2][BN*BK];
  int tid = threadIdx.x, wid = tid >> 6, lane = tid & 63;
  int m0 = blockIdx.x * BM, n0 = blockIdx.y * BN;

  f32x4 acc[4][4] = {};
  int wm = (wid >> 1) * 64, wn = (wid & 1) * 64;

  auto stage = [&](int buf, int k0) {
#pragma unroll
    for (int t = 0; t < 4; ++t) {
      int chunk = wid*4 + t;
      gl2lds16(A + (size_t)(m0 + chunk*8 + (lane>>3))*lda + k0 + (lane&7)*8,
               (void*)(&As[buf][chunk*512]));
      gl2lds16(Bm + (size_t)(n0 + chunk*8 + (lane>>3))*ldb + k0 + (lane&7)*8,
               (void*)(&Bs[buf][chunk*512]));
    }
  };

  stage(0, 0);
  __syncthreads();
  int cur = 0;
  for (int kt = 0; kt < 8; ++kt) {
    if (kt + 1 < 8) stage(cur ^ 1, (kt + 1) * BK);
#pragma unroll
    for (int ks = 0; ks < BK; ks += 32) {
      s16x8 af[4], bfr[4];
#pragma unroll
      for (int mi = 0; mi < 4; ++mi)
        af[mi] = *reinterpret_cast<const s16x8*>(&As[cur][(wm + mi*16 + (lane&15))*BK + ks + (lane>>4)*8]);
#pragma unroll
      for (int ni = 0; ni < 4; ++ni)
        bfr[ni] = *reinterpret_cast<const s16x8*>(&Bs[cur][(wn + ni*16 + (lane&15))*BK + ks + (lane>>4)*8]);
#pragma unroll
      for (int mi = 0; mi < 4; ++mi)
#pragma unroll
        for (int ni = 0; ni < 4; ++ni)
          acc[mi][ni] = __builtin_amdgcn_mfma_f32_16x16x32_bf16(af[mi], bfr[ni], acc[mi][ni], 0, 0, 0);
    }
    __syncthreads();
    cur ^= 1;
  }

  // n0 selects exactly one of q/k/v (128-col tile within 512-col segment)
  u16* Odst; int cbase;
  if (n0 < 512)       { Odst = Oq; cbase = n0; }
  else if (n0 < 1024) { Odst = Ok; cbase = n0 - 512; }
  else                { Odst = Ov; cbase = n0 - 1024; }
#pragma unroll
  for (int mi = 0; mi < 4; ++mi) {
#pragma unroll
    for (int ni = 0; ni < 4; ++ni) {
      int col = n0 + wn + ni*16 + (lane&15);
      int c   = cbase + wn + ni*16 + (lane&15);
      float bi = bias[col];
#pragma unroll
      for (int r = 0; r < 4; ++r) {
        int row = m0 + wm + mi*16 + (lane>>4)*4 + r;
        Odst[(size_t)row*512 + c] = f2b(acc[mi][ni][r] + bi);
      }
    }
  }
}

// ---------------- fused: k row-softmax + transpose, v transpose ----------------
// in: k[b][n][c], v[b][n][c] ; out: kT[b][c][n] (softmaxed over c), vT[b][c][n]
__global__ __launch_bounds__(256) void kv_transform(const u16* __restrict__ kin,
                                                    const u16* __restrict__ vin,
                                                    u16* __restrict__ kT,
                                                    u16* __restrict__ vT) {
  __shared__ u16 T[32][516];  // row stride 1032 B (8B-aligned for ull stores)
  int b = blockIdx.x, n0 = blockIdx.y * 32;
  int wid = threadIdx.x >> 6, lane = threadIdx.x & 63;

  // ---- phase 1: k softmax + transpose
#pragma unroll
  for (int i = 0; i < 8; ++i) {
    int r = wid * 8 + i;
    const u16* p = kin + ((size_t)(b*N_ + n0 + r))*C_;
    s16x8 raw = reinterpret_cast<const s16x8*>(p)[lane];
    float v[8]; float m = -3e38f;
#pragma unroll
    for (int j = 0; j < 8; ++j) { v[j] = b2f((u16)raw[j]); m = fmaxf(m, v[j]); }
    for (int off = 32; off; off >>= 1) m = fmaxf(m, __shfl_xor(m, off));
    float s = 0.f;
#pragma unroll
    for (int j = 0; j < 8; ++j) { v[j] = __expf(v[j] - m); s += v[j]; }
    for (int off = 32; off; off >>= 1) s += __shfl_xor(s, off);
    float inv = 1.f / s;
    union { s16x8 v8; unsigned long long d[2]; } o;
#pragma unroll
    for (int j = 0; j < 8; ++j) o.v8[j] = (short)f2b(v[j] * inv);
    unsigned long long* dst = reinterpret_cast<unsigned long long*>(&T[r][lane*8]);
    dst[0] = o.d[0]; dst[1] = o.d[1];
  }
  __syncthreads();
#pragma unroll
  for (int h = 0; h < 2; ++h) {
    int c = h*256 + threadIdx.x;
    u16* dst = kT + ((size_t)(b*C_ + c))*N_ + n0;
#pragma unroll
    for (int q4 = 0; q4 < 4; ++q4) {
      s16x8 o;
#pragma unroll
      for (int j = 0; j < 8; ++j) o[j] = (short)T[q4*8 + j][c];
      reinterpret_cast<s16x8*>(dst)[q4] = o;
    }
  }
  __syncthreads();

  // ---- phase 2: v transpose
#pragma unroll
  for (int i = 0; i < 8; ++i) {
    int r = wid * 8 + i;
    const u16* p = vin + ((size_t)(b*N_ + n0 + r))*C_;
    union { s16x8 v8; unsigned long long d[2]; } o;
    o.v8 = reinterpret_cast<const s16x8*>(p)[lane];
    unsigned long long* dst = reinterpret_cast<unsigned long long*>(&T[r][lane*8]);
    dst[0] = o.d[0]; dst[1] = o.d[1];
  }
  __syncthreads();
#pragma unroll
  for (int h = 0; h < 2; ++h) {
    int c = h*256 + threadIdx.x;
    u16* dst = vT + ((size_t)(b*C_ + c))*N_ + n0;
#pragma unroll
    for (int q4 = 0; q4 < 4; ++q4) {
      s16x8 o;
#pragma unroll
      for (int j = 0; j < 8; ++j) o[j] = (short)T[q4*8 + j][c];
      reinterpret_cast<s16x8*>(dst)[q4] = o;
    }
  }
}

// ---------------- q softmax over tokens (columns), bf16 ----------------
__global__ __launch_bounds__(256) void q_part(const u16* __restrict__ q,
                                              float* __restrict__ qms) {
  int b = blockIdx.x, c = blockIdx.y*256 + threadIdx.x, sp = blockIdx.z;
  const u16* col = q + (size_t)b*N_*C_ + c;
  float m = -3e38f, s = 0.f;
#pragma unroll 8
  for (int i = 0; i < 128; ++i) {
    float v = b2f(col[(size_t)(sp*128 + i)*C_]);
    float nm = fmaxf(m, v);
    s = s*__expf(m - nm) + __expf(v - nm);
    m = nm;
  }
  size_t o = ((size_t)(b*C_ + c)*8 + sp)*2;
  qms[o] = m; qms[o+1] = s;
}

__global__ __launch_bounds__(256) void q_apply(const u16* __restrict__ q,
                                               const float* __restrict__ qms,
                                               u16* __restrict__ qs) {
  int b = blockIdx.x, c = blockIdx.y*256 + threadIdx.x, sp = blockIdx.z;
  const float* pm = qms + (size_t)(b*C_ + c)*16;
  float M = -3e38f;
#pragma unroll
  for (int i = 0; i < 8; ++i) M = fmaxf(M, pm[i*2]);
  float S = 0.f;
#pragma unroll
  for (int i = 0; i < 8; ++i) S += pm[i*2+1] * __expf(pm[i*2] - M);
  float inv = 1.f / S;
  const u16* col = q + (size_t)b*N_*C_ + c;
  u16* ocol = qs + (size_t)b*N_*C_ + c;
#pragma unroll 8
  for (int i = 0; i < 128; ++i) {
    size_t n = (size_t)(sp*128 + i)*C_;
    ocol[n] = f2b(__expf(b2f(col[n]) - M) * inv);
  }
}

// ---------------- launch ----------------
extern "C" void kernel_launch(void* const* d_in, const int* in_sizes, int n_in,
                              void* d_out, int out_size, void* d_ws, size_t ws_size,
                              hipStream_t stream) {
  (void)in_sizes; (void)n_in; (void)out_size; (void)ws_size;
  const float* x      = (const float*)d_in[0];
  const float* gn_w   = (const float*)d_in[1];
  const float* gn_b   = (const float*)d_in[2];
  const float* qkv_w  = (const float*)d_in[3];
  const float* qkv_b  = (const float*)d_in[4];
  const float* proj_w = (const float*)d_in[5];
  const float* proj_b = (const float*)d_in[6];

  char* ws = (char*)d_ws;
  float* xn   = (float*)(ws + OFF_XN);
  u16*   xnT  = (u16*)  (ws + OFF_XNT);
  u16*   qb   = (u16*)  (ws + OFF_Q);
  u16*   kb   = (u16*)  (ws + OFF_K);
  u16*   vb   = (u16*)  (ws + OFF_V);
  u16*   kT   = (u16*)  (ws + OFF_KT);
  u16*   vT   = (u16*)  (ws + OFF_VT);
  u16*   qsb  = (u16*)  (ws + OFF_QS);
  u16*   ctxT = (u16*)  (ws + OFF_CTXT);
  u16*   att  = (u16*)  (ws + OFF_ATT);
  u16*   wq   = (u16*)  (ws + OFF_WQ);
  u16*   wp   = (u16*)  (ws + OFF_WP);
  float* gnp  = (float*)(ws + OFF_GNP);
  float* qms  = (float*)(ws + OFF_QMS);

  gn_partial<<<dim3(64, 8), 256, 0, stream>>>(x, gnp);
  gn_apply<<<dim3(8, 8, 16), 256, 0, stream>>>(x, gn_w, gn_b, gnp, xn, xnT);

  cvt_w<<<dim3(768), 256, 0, stream>>>(qkv_w, wq, 1536*512/4);
  cvt_w<<<dim3(256), 256, 0, stream>>>(proj_w, wp, 512*512/4);

  // qkv: [8192,512] x [1536,512]^T -> q,k,v bf16 [tok][c] (all coalesced)
  gemm_qkv<<<dim3(64, 12), 256, 0, stream>>>(xnT, wq, qkv_b, qb, kb, vb);

  kv_transform<<<dim3(8, 32), 256, 0, stream>>>(kb, vb, kT, vT);
  q_part<<<dim3(8, 2, 8), 256, 0, stream>>>(qb, qms);
  q_apply<<<dim3(8, 2, 8), 256, 0, stream>>>(qb, qms, qsb);

  // ctxT[b][d][c] = sum_n vT[b][d][n] * kT[b][c][n]
  gemm<1><<<dim3(4, 4, 8), 256, 0, stream>>>(vT, kT, 512, 512, 1024, 1024, 1024,
                                             524288, 524288, 262144, nullptr, ctxT, nullptr);
  // att[b][n][d] = sum_c qs[b][n][c] * ctxT[b][d][c]
  gemm<1><<<dim3(8, 4, 8), 256, 0, stream>>>(qsb, ctxT, 1024, 512, 512, 512, 512,
                                             524288, 262144, 524288, nullptr, att, nullptr);
  // proj + bias + residual + transpose: out[b][c][n] = att·wp^T + proj_b + xn
  gemm<2><<<dim3(64, 4), 256, 0, stream>>>(att, wp, 8192, 512, 512, 512, 512,
                                           0, 0, 0, proj_b, (float*)d_out, xn);
}

// Round 4
// 185.518 us; speedup vs baseline: 1.1686x; 1.0934x over previous
//
#include <hip/hip_runtime.h>
#include <hip/hip_bf16.h>
#include <stdint.h>

typedef unsigned short u16;
typedef __attribute__((ext_vector_type(8))) short s16x8;
typedef __attribute__((ext_vector_type(4))) float f32x4;
typedef __attribute__((ext_vector_type(4))) unsigned short u16x4;

static constexpr int B_ = 8, C_ = 512, N_ = 1024, G_ = 8;
static constexpr float EPS = 1e-5f;

// ---------------- workspace layout (bytes) ----------------
static constexpr size_t OFF_XNT  = 0;                                   // bf16 [B][N][C] groupnorm out (residual + GEMM A)
static constexpr size_t OFF_Q    = OFF_XNT  + (size_t)B_*N_*C_*2;       // bf16 [B][N][C] q raw
static constexpr size_t OFF_K    = OFF_Q    + (size_t)B_*N_*C_*2;       // bf16 [B][N][C] k raw
static constexpr size_t OFF_V    = OFF_K    + (size_t)B_*N_*C_*2;       // bf16 [B][N][C] v raw
static constexpr size_t OFF_KT   = OFF_V    + (size_t)B_*N_*C_*2;       // bf16 [B][C][N] softmax(k)^T
static constexpr size_t OFF_VT   = OFF_KT   + (size_t)B_*N_*C_*2;       // bf16 [B][C][N] v^T
static constexpr size_t OFF_QS   = OFF_VT   + (size_t)B_*N_*C_*2;       // bf16 [B][N][C] softmax(q)
static constexpr size_t OFF_CTXT = OFF_QS   + (size_t)B_*N_*C_*2;       // bf16 [B][C][C] ctx^T [d][c]
static constexpr size_t OFF_ATT  = OFF_CTXT + (size_t)B_*C_*C_*2;       // bf16 [B][N][C]
static constexpr size_t OFF_WQ   = OFF_ATT  + (size_t)B_*N_*C_*2;       // bf16 [1536][512]
static constexpr size_t OFF_WP   = OFF_WQ   + (size_t)3*C_*C_*2;        // bf16 [512][512]
static constexpr size_t OFF_GNP  = OFF_WP   + (size_t)C_*C_*2;          // f32 [64][8][2]

// ---------------- helpers ----------------
__device__ __forceinline__ float b2f(u16 u) {
  union { float f; uint32_t i; } x; x.i = ((uint32_t)u) << 16; return x.f;
}
__device__ __forceinline__ u16 f2b(float f) {
  union { float f; uint32_t i; } x; x.f = f;
  return (u16)((x.i + 0x7fffu + ((x.i >> 16) & 1u)) >> 16);
}
#define AS1 __attribute__((address_space(1)))
#define AS3 __attribute__((address_space(3)))
__device__ __forceinline__ void gl2lds16(const void* g, void* l) {
  __builtin_amdgcn_global_load_lds((const AS1 void*)g, (AS3 void*)l, 16, 0, 0);
}

// ---------------- groupnorm ----------------
__global__ __launch_bounds__(256) void gn_partial(const float* __restrict__ x,
                                                  float* __restrict__ gnp) {
  int bg = blockIdx.x;      // 64 = B*G
  int chunk = blockIdx.y;   // 8 chunks of 8192 floats
  const float4* p = reinterpret_cast<const float4*>(x + (size_t)bg * 65536 + (size_t)chunk * 8192);
  int tid = threadIdx.x;
  float s = 0.f, sq = 0.f;
#pragma unroll
  for (int i = 0; i < 8; ++i) {
    float4 v = p[i * 256 + tid];
    s  += v.x + v.y + v.z + v.w;
    sq += v.x*v.x + v.y*v.y + v.z*v.z + v.w*v.w;
  }
  for (int off = 32; off; off >>= 1) { s += __shfl_xor(s, off); sq += __shfl_xor(sq, off); }
  __shared__ float red[8];
  int wid = tid >> 6, lane = tid & 63;
  if (lane == 0) { red[wid*2] = s; red[wid*2+1] = sq; }
  __syncthreads();
  if (tid == 0) {
    gnp[(bg*8 + chunk)*2 + 0] = red[0]+red[2]+red[4]+red[6];
    gnp[(bg*8 + chunk)*2 + 1] = red[1]+red[3]+red[5]+red[7];
  }
}

// reads x [b][c][n], writes ONLY xnT bf16 [b][n][c] (residual read transposed later)
__global__ __launch_bounds__(256) void gn_apply(const float* __restrict__ x,
                                                const float* __restrict__ gw,
                                                const float* __restrict__ gb,
                                                const float* __restrict__ gnp,
                                                u16* __restrict__ xnT) {
  __shared__ float T[64][65];
  int b = blockIdx.x, c0 = blockIdx.y * 64, n0 = blockIdx.z * 64;
  int bg = b * G_ + blockIdx.y;
  float S = 0.f, SQ = 0.f;
#pragma unroll
  for (int i = 0; i < 8; ++i) { S += gnp[(bg*8+i)*2]; SQ += gnp[(bg*8+i)*2+1]; }
  float mean = S * (1.f/65536.f);
  float var  = SQ * (1.f/65536.f) - mean*mean;
  float rstd = rsqrtf(var + EPS);
  int tn = threadIdx.x & 63, tc = threadIdx.x >> 6;
#pragma unroll 4
  for (int it = 0; it < 16; ++it) {
    int cl = it*4 + tc;
    int c = c0 + cl;
    float v = x[((size_t)b*C_ + c)*N_ + n0 + tn];
    T[tn][cl] = (v - mean) * rstd * gw[c] + gb[c];
  }
  __syncthreads();
#pragma unroll
  for (int p = 0; p < 2; ++p) {
    int nl = p*32 + (threadIdx.x >> 3);
    int cs = (threadIdx.x & 7) * 8;
    s16x8 o;
#pragma unroll
    for (int j = 0; j < 8; ++j) o[j] = (short)f2b(T[nl][cs + j]);
    *reinterpret_cast<s16x8*>(&xnT[((size_t)(b*N_ + n0 + nl))*C_ + c0 + cs]) = o;
  }
}

// ---------------- weights fp32 -> bf16 (both in one launch) ----------------
__global__ __launch_bounds__(256) void cvt_w2(const float* __restrict__ w1,
                                              const float* __restrict__ w2,
                                              u16* __restrict__ o1,
                                              u16* __restrict__ o2) {
  int i = blockIdx.x * 256 + threadIdx.x;
  const int n1 = 1536*512/4;
  if (i < n1) {
    float4 v = reinterpret_cast<const float4*>(w1)[i];
    u16x4 r = { f2b(v.x), f2b(v.y), f2b(v.z), f2b(v.w) };
    reinterpret_cast<u16x4*>(o1)[i] = r;
  } else {
    int j = i - n1;   // < 512*512/4
    float4 v = reinterpret_cast<const float4*>(w2)[j];
    u16x4 r = { f2b(v.x), f2b(v.y), f2b(v.z), f2b(v.w) };
    reinterpret_cast<u16x4*>(o2)[j] = r;
  }
}

// ---------------- GEMM core (A K-contig, B^T K-contig), dbuf + T2 swizzle ----------------
// LDS tile [128 rows][64 k] u16; slot = 16B (8 u16). Swizzle: LDS[r][sl] holds
// global slot sl ^ (r&7). Staged via pre-swizzled GLOBAL source (rule #21),
// read back with the same XOR -> conflict-free ds_read_b128.
// EPI 1: bf16 out O0 [row][col], ld=N, batch strideC
// EPI 2: proj: f32 out O0 in [b][col][n] + bias + bf16 residual from R (xnT [b][n][c])
template<int EPI>
__global__ __launch_bounds__(256) void gemm(const u16* __restrict__ A,
                                            const u16* __restrict__ Bm,
                                            int M, int N, int K, int lda, int ldb,
                                            long strideA, long strideB, long strideC,
                                            const float* __restrict__ bias,
                                            void* __restrict__ O0,
                                            const void* __restrict__ R) {
  constexpr int BM = 128, BN = 128, BK = 64;
  __shared__ u16 As[2][BM*BK];
  __shared__ u16 Bs[2][BN*BK];
  int tid = threadIdx.x, wid = tid >> 6, lane = tid & 63;
  int m0 = blockIdx.x * BM, n0 = blockIdx.y * BN;
  const u16* Ab = A + (size_t)strideA * blockIdx.z;
  const u16* Bp = Bm + (size_t)strideB * blockIdx.z;

  f32x4 acc[4][4] = {};
  int wm = (wid >> 1) * 64, wn = (wid & 1) * 64;
  int sr = lane >> 3;                 // row within 8-row chunk
  int sg = (lane & 7) ^ sr;           // pre-swizzled global k-slot

  auto stage = [&](int buf, int k0) {
#pragma unroll
    for (int t = 0; t < 4; ++t) {
      int chunk = wid*4 + t;
      gl2lds16(Ab + (size_t)(m0 + chunk*8 + sr)*lda + k0 + sg*8,
               (void*)(&As[buf][chunk*512]));
      gl2lds16(Bp + (size_t)(n0 + chunk*8 + sr)*ldb + k0 + sg*8,
               (void*)(&Bs[buf][chunk*512]));
    }
  };

  int KT = K / BK;
  stage(0, 0);
  __syncthreads();
  int cur = 0;
  for (int kt = 0; kt < KT; ++kt) {
    if (kt + 1 < KT) stage(cur ^ 1, (kt + 1) * BK);   // prefetch overlaps compute
#pragma unroll
    for (int ks = 0; ks < BK; ks += 32) {
      int s = (ks >> 3) + (lane >> 4);                // 16B slot index 0..7
      s16x8 af[4], bfr[4];
#pragma unroll
      for (int mi = 0; mi < 4; ++mi) {
        int ar = wm + mi*16 + (lane & 15);
        af[mi] = *reinterpret_cast<const s16x8*>(&As[cur][ar*64 + ((s ^ (ar & 7)) << 3)]);
      }
#pragma unroll
      for (int ni = 0; ni < 4; ++ni) {
        int br = wn + ni*16 + (lane & 15);
        bfr[ni] = *reinterpret_cast<const s16x8*>(&Bs[cur][br*64 + ((s ^ (br & 7)) << 3)]);
      }
#pragma unroll
      for (int mi = 0; mi < 4; ++mi)
#pragma unroll
        for (int ni = 0; ni < 4; ++ni)
          acc[mi][ni] = __builtin_amdgcn_mfma_f32_16x16x32_bf16(af[mi], bfr[ni], acc[mi][ni], 0, 0, 0);
    }
    __syncthreads();
    cur ^= 1;
  }

#pragma unroll
  for (int mi = 0; mi < 4; ++mi) {
#pragma unroll
    for (int ni = 0; ni < 4; ++ni) {
      int col = n0 + wn + ni*16 + (lane & 15);
      if constexpr (EPI == 2) {
        int rowb = m0 + wm + mi*16 + (lane >> 4)*4;
        int b = rowb >> 10, n = rowb & 1023;
        const u16* xr = (const u16*)R + ((size_t)(b*N_ + n))*C_ + col;
        size_t idx = (size_t)b*524288 + (size_t)col*1024 + n;
        float bi = bias[col];
        float4 o;
        o.x = acc[mi][ni][0] + bi + b2f(xr[0]);
        o.y = acc[mi][ni][1] + bi + b2f(xr[512]);
        o.z = acc[mi][ni][2] + bi + b2f(xr[1024]);
        o.w = acc[mi][ni][3] + bi + b2f(xr[1536]);
        *reinterpret_cast<float4*>((float*)O0 + idx) = o;
      } else {
#pragma unroll
        for (int r = 0; r < 4; ++r) {
          int row = m0 + wm + mi*16 + (lane >> 4)*4 + r;
          ((u16*)O0)[(size_t)strideC*blockIdx.z + (size_t)row*N + col] = f2b(acc[mi][ni][r]);
        }
      }
    }
  }
}

// ---------------- qkv GEMM (same core, 3-way split epilogue) ----------------
__global__ __launch_bounds__(256) void gemm_qkv(const u16* __restrict__ A,
                                                const u16* __restrict__ Bm,
                                                const float* __restrict__ bias,
                                                u16* __restrict__ Oq,
                                                u16* __restrict__ Ok,
                                                u16* __restrict__ Ov) {
  constexpr int BM = 128, BN = 128, BK = 64;
  const int lda = 512, ldb = 512;
  __shared__ u16 As[2][BM*BK];
  __shared__ u16 Bs[2][BN*BK];
  int tid = threadIdx.x, wid = tid >> 6, lane = tid & 63;
  int m0 = blockIdx.x * BM, n0 = blockIdx.y * BN;

  f32x4 acc[4][4] = {};
  int wm = (wid >> 1) * 64, wn = (wid & 1) * 64;
  int sr = lane >> 3;
  int sg = (lane & 7) ^ sr;

  auto stage = [&](int buf, int k0) {
#pragma unroll
    for (int t = 0; t < 4; ++t) {
      int chunk = wid*4 + t;
      gl2lds16(A + (size_t)(m0 + chunk*8 + sr)*lda + k0 + sg*8,
               (void*)(&As[buf][chunk*512]));
      gl2lds16(Bm + (size_t)(n0 + chunk*8 + sr)*ldb + k0 + sg*8,
               (void*)(&Bs[buf][chunk*512]));
    }
  };

  stage(0, 0);
  __syncthreads();
  int cur = 0;
  for (int kt = 0; kt < 8; ++kt) {
    if (kt + 1 < 8) stage(cur ^ 1, (kt + 1) * BK);
#pragma unroll
    for (int ks = 0; ks < BK; ks += 32) {
      int s = (ks >> 3) + (lane >> 4);
      s16x8 af[4], bfr[4];
#pragma unroll
      for (int mi = 0; mi < 4; ++mi) {
        int ar = wm + mi*16 + (lane & 15);
        af[mi] = *reinterpret_cast<const s16x8*>(&As[cur][ar*64 + ((s ^ (ar & 7)) << 3)]);
      }
#pragma unroll
      for (int ni = 0; ni < 4; ++ni) {
        int br = wn + ni*16 + (lane & 15);
        bfr[ni] = *reinterpret_cast<const s16x8*>(&Bs[cur][br*64 + ((s ^ (br & 7)) << 3)]);
      }
#pragma unroll
      for (int mi = 0; mi < 4; ++mi)
#pragma unroll
        for (int ni = 0; ni < 4; ++ni)
          acc[mi][ni] = __builtin_amdgcn_mfma_f32_16x16x32_bf16(af[mi], bfr[ni], acc[mi][ni], 0, 0, 0);
    }
    __syncthreads();
    cur ^= 1;
  }

  u16* Odst; int cbase;
  if (n0 < 512)       { Odst = Oq; cbase = n0; }
  else if (n0 < 1024) { Odst = Ok; cbase = n0 - 512; }
  else                { Odst = Ov; cbase = n0 - 1024; }
#pragma unroll
  for (int mi = 0; mi < 4; ++mi) {
#pragma unroll
    for (int ni = 0; ni < 4; ++ni) {
      int col = n0 + wn + ni*16 + (lane & 15);
      int c   = cbase + wn + ni*16 + (lane & 15);
      float bi = bias[col];
#pragma unroll
      for (int r = 0; r < 4; ++r) {
        int row = m0 + wm + mi*16 + (lane >> 4)*4 + r;
        Odst[(size_t)row*512 + c] = f2b(acc[mi][ni][r] + bi);
      }
    }
  }
}

// ---------------- fused: k row-softmax + transpose, v transpose ----------------
__global__ __launch_bounds__(256) void kv_transform(const u16* __restrict__ kin,
                                                    const u16* __restrict__ vin,
                                                    u16* __restrict__ kT,
                                                    u16* __restrict__ vT) {
  __shared__ u16 T[32][516];
  int b = blockIdx.x, n0 = blockIdx.y * 32;
  int wid = threadIdx.x >> 6, lane = threadIdx.x & 63;

  // ---- phase 1: k softmax + transpose
#pragma unroll
  for (int i = 0; i < 8; ++i) {
    int r = wid * 8 + i;
    const u16* p = kin + ((size_t)(b*N_ + n0 + r))*C_;
    s16x8 raw = reinterpret_cast<const s16x8*>(p)[lane];
    float v[8]; float m = -3e38f;
#pragma unroll
    for (int j = 0; j < 8; ++j) { v[j] = b2f((u16)raw[j]); m = fmaxf(m, v[j]); }
    for (int off = 32; off; off >>= 1) m = fmaxf(m, __shfl_xor(m, off));
    float s = 0.f;
#pragma unroll
    for (int j = 0; j < 8; ++j) { v[j] = __expf(v[j] - m); s += v[j]; }
    for (int off = 32; off; off >>= 1) s += __shfl_xor(s, off);
    float inv = 1.f / s;
    union { s16x8 v8; unsigned long long d[2]; } o;
#pragma unroll
    for (int j = 0; j < 8; ++j) o.v8[j] = (short)f2b(v[j] * inv);
    unsigned long long* dst = reinterpret_cast<unsigned long long*>(&T[r][lane*8]);
    dst[0] = o.d[0]; dst[1] = o.d[1];
  }
  __syncthreads();
#pragma unroll
  for (int h = 0; h < 2; ++h) {
    int c = h*256 + threadIdx.x;
    u16* dst = kT + ((size_t)(b*C_ + c))*N_ + n0;
#pragma unroll
    for (int q4 = 0; q4 < 4; ++q4) {
      s16x8 o;
#pragma unroll
      for (int j = 0; j < 8; ++j) o[j] = (short)T[q4*8 + j][c];
      reinterpret_cast<s16x8*>(dst)[q4] = o;
    }
  }
  __syncthreads();

  // ---- phase 2: v transpose
#pragma unroll
  for (int i = 0; i < 8; ++i) {
    int r = wid * 8 + i;
    const u16* p = vin + ((size_t)(b*N_ + n0 + r))*C_;
    union { s16x8 v8; unsigned long long d[2]; } o;
    o.v8 = reinterpret_cast<const s16x8*>(p)[lane];
    unsigned long long* dst = reinterpret_cast<unsigned long long*>(&T[r][lane*8]);
    dst[0] = o.d[0]; dst[1] = o.d[1];
  }
  __syncthreads();
#pragma unroll
  for (int h = 0; h < 2; ++h) {
    int c = h*256 + threadIdx.x;
    u16* dst = vT + ((size_t)(b*C_ + c))*N_ + n0;
#pragma unroll
    for (int q4 = 0; q4 < 4; ++q4) {
      s16x8 o;
#pragma unroll
      for (int j = 0; j < 8; ++j) o[j] = (short)T[q4*8 + j][c];
      reinterpret_cast<s16x8*>(dst)[q4] = o;
    }
  }
}

// ---------------- q softmax over tokens (columns), single kernel ----------------
// grid (B, C/32); block 256 = 4cg x 64rw. 16B/lane vectorized loads.
__global__ __launch_bounds__(256) void q_softmax(const u16* __restrict__ q,
                                                 u16* __restrict__ qs) {
  int b = blockIdx.x, c0 = blockIdx.y * 32;
  int t = threadIdx.x;
  int cg = t & 3;           // 8-channel group within the 32
  int rw = t >> 2;          // 0..63: row stride
  const u16* base = q + (size_t)b*N_*C_ + c0 + cg*8;
  float m[8], s[8];
#pragma unroll
  for (int j = 0; j < 8; ++j) { m[j] = -3e38f; s[j] = 0.f; }
  for (int it = 0; it < 16; ++it) {
    int n = it*64 + rw;
    s16x8 raw = *reinterpret_cast<const s16x8*>(base + (size_t)n*C_);
#pragma unroll
    for (int j = 0; j < 8; ++j) {
      float v = b2f((u16)raw[j]);
      float nm = fmaxf(m[j], v);
      s[j] = s[j]*__expf(m[j] - nm) + __expf(v - nm);
      m[j] = nm;
    }
  }
  __shared__ float Mr[32][65], Sr[32][65];
#pragma unroll
  for (int j = 0; j < 8; ++j) { Mr[cg*8 + j][rw] = m[j]; Sr[cg*8 + j][rw] = s[j]; }
  __syncthreads();
  __shared__ float MS[32][2];
  if (t < 32) {
    float M = -3e38f;
    for (int i = 0; i < 64; ++i) M = fmaxf(M, Mr[t][i]);
    float S = 0.f;
    for (int i = 0; i < 64; ++i) S += Sr[t][i]*__expf(Mr[t][i] - M);
    MS[t][0] = M; MS[t][1] = 1.f / S;
  }
  __syncthreads();
  float Mv[8], Iv[8];
#pragma unroll
  for (int j = 0; j < 8; ++j) { Mv[j] = MS[cg*8 + j][0]; Iv[j] = MS[cg*8 + j][1]; }
  u16* ob = qs + (size_t)b*N_*C_ + c0 + cg*8;
  for (int it = 0; it < 16; ++it) {
    int n = it*64 + rw;
    s16x8 raw = *reinterpret_cast<const s16x8*>(base + (size_t)n*C_);
    s16x8 o;
#pragma unroll
    for (int j = 0; j < 8; ++j)
      o[j] = (short)f2b(__expf(b2f((u16)raw[j]) - Mv[j]) * Iv[j]);
    *reinterpret_cast<s16x8*>(ob + (size_t)n*C_) = o;
  }
}

// ---------------- launch ----------------
extern "C" void kernel_launch(void* const* d_in, const int* in_sizes, int n_in,
                              void* d_out, int out_size, void* d_ws, size_t ws_size,
                              hipStream_t stream) {
  (void)in_sizes; (void)n_in; (void)out_size; (void)ws_size;
  const float* x      = (const float*)d_in[0];
  const float* gn_w   = (const float*)d_in[1];
  const float* gn_b   = (const float*)d_in[2];
  const float* qkv_w  = (const float*)d_in[3];
  const float* qkv_b  = (const float*)d_in[4];
  const float* proj_w = (const float*)d_in[5];
  const float* proj_b = (const float*)d_in[6];

  char* ws = (char*)d_ws;
  u16*   xnT  = (u16*)  (ws + OFF_XNT);
  u16*   qb   = (u16*)  (ws + OFF_Q);
  u16*   kb   = (u16*)  (ws + OFF_K);
  u16*   vb   = (u16*)  (ws + OFF_V);
  u16*   kT   = (u16*)  (ws + OFF_KT);
  u16*   vT   = (u16*)  (ws + OFF_VT);
  u16*   qsb  = (u16*)  (ws + OFF_QS);
  u16*   ctxT = (u16*)  (ws + OFF_CTXT);
  u16*   att  = (u16*)  (ws + OFF_ATT);
  u16*   wq   = (u16*)  (ws + OFF_WQ);
  u16*   wp   = (u16*)  (ws + OFF_WP);
  float* gnp  = (float*)(ws + OFF_GNP);

  gn_partial<<<dim3(64, 8), 256, 0, stream>>>(x, gnp);
  gn_apply<<<dim3(8, 8, 16), 256, 0, stream>>>(x, gn_w, gn_b, gnp, xnT);

  cvt_w2<<<dim3(1024), 256, 0, stream>>>(qkv_w, proj_w, wq, wp);

  // qkv: [8192,512] x [1536,512]^T -> q,k,v bf16 [tok][c]
  gemm_qkv<<<dim3(64, 12), 256, 0, stream>>>(xnT, wq, qkv_b, qb, kb, vb);

  kv_transform<<<dim3(8, 32), 256, 0, stream>>>(kb, vb, kT, vT);
  q_softmax<<<dim3(8, 16), 256, 0, stream>>>(qb, qsb);

  // ctxT[b][d][c] = sum_n vT[b][d][n] * kT[b][c][n]
  gemm<1><<<dim3(4, 4, 8), 256, 0, stream>>>(vT, kT, 512, 512, 1024, 1024, 1024,
                                             524288, 524288, 262144, nullptr, ctxT, nullptr);
  // att[b][n][d] = sum_c qs[b][n][c] * ctxT[b][d][c]
  gemm<1><<<dim3(8, 4, 8), 256, 0, stream>>>(qsb, ctxT, 1024, 512, 512, 512, 512,
                                             524288, 262144, 524288, nullptr, att, nullptr);
  // proj + bias + residual(xnT, transposed read) -> out[b][c][n] f32
  gemm<2><<<dim3(64, 4), 256, 0, stream>>>(att, wp, 8192, 512, 512, 512, 512,
                                           0, 0, 0, proj_b, (float*)d_out, xnT);
}

// Round 5
// 172.202 us; speedup vs baseline: 1.2589x; 1.0773x over previous
//
#include <hip/hip_runtime.h>
#include <hip/hip_bf16.h>
#include <stdint.h>

typedef unsigned short u16;
typedef __attribute__((ext_vector_type(8))) short s16x8;
typedef __attribute__((ext_vector_type(4))) float f32x4;
typedef __attribute__((ext_vector_type(4))) unsigned short u16x4;

static constexpr int B_ = 8, C_ = 512, N_ = 1024, G_ = 8;
static constexpr float EPS = 1e-5f;

// ---------------- workspace layout (bytes) ----------------
static constexpr size_t OFF_XNT  = 0;                                   // bf16 [B][N][C] groupnorm out (residual + GEMM A)
static constexpr size_t OFF_Q    = OFF_XNT  + (size_t)B_*N_*C_*2;       // bf16 [B][N][C] q raw
static constexpr size_t OFF_K    = OFF_Q    + (size_t)B_*N_*C_*2;       // bf16 [B][N][C] k raw
static constexpr size_t OFF_V    = OFF_K    + (size_t)B_*N_*C_*2;       // bf16 [B][N][C] v raw
static constexpr size_t OFF_KT   = OFF_V    + (size_t)B_*N_*C_*2;       // bf16 [B][C][N] softmax(k)^T
static constexpr size_t OFF_VT   = OFF_KT   + (size_t)B_*N_*C_*2;       // bf16 [B][C][N] v^T
static constexpr size_t OFF_QS   = OFF_VT   + (size_t)B_*N_*C_*2;       // bf16 [B][N][C] softmax(q)
static constexpr size_t OFF_CTX  = OFF_QS   + (size_t)B_*N_*C_*2;       // bf16 [B][C][C] ctx [c][d]
static constexpr size_t OFF_MT   = OFF_CTX  + (size_t)B_*C_*C_*2;       // bf16 [B][C][C] (ctx@wp^T)^T : [e][c]
static constexpr size_t OFF_WQ   = OFF_MT   + (size_t)B_*C_*C_*2;       // bf16 [1536][512]
static constexpr size_t OFF_WP   = OFF_WQ   + (size_t)3*C_*C_*2;        // bf16 [512][512]
static constexpr size_t OFF_GNP  = OFF_WP   + (size_t)C_*C_*2;          // f32 [64][8][2]

// ---------------- helpers ----------------
__device__ __forceinline__ float b2f(u16 u) {
  union { float f; uint32_t i; } x; x.i = ((uint32_t)u) << 16; return x.f;
}
__device__ __forceinline__ u16 f2b(float f) {
  union { float f; uint32_t i; } x; x.f = f;
  return (u16)((x.i + 0x7fffu + ((x.i >> 16) & 1u)) >> 16);
}
#define AS1 __attribute__((address_space(1)))
#define AS3 __attribute__((address_space(3)))
__device__ __forceinline__ void gl2lds16(const void* g, void* l) {
  __builtin_amdgcn_global_load_lds((const AS1 void*)g, (AS3 void*)l, 16, 0, 0);
}

// ---------------- groupnorm ----------------
__global__ __launch_bounds__(256) void gn_partial(const float* __restrict__ x,
                                                  float* __restrict__ gnp) {
  int bg = blockIdx.x;      // 64 = B*G
  int chunk = blockIdx.y;   // 8 chunks of 8192 floats
  const float4* p = reinterpret_cast<const float4*>(x + (size_t)bg * 65536 + (size_t)chunk * 8192);
  int tid = threadIdx.x;
  float s = 0.f, sq = 0.f;
#pragma unroll
  for (int i = 0; i < 8; ++i) {
    float4 v = p[i * 256 + tid];
    s  += v.x + v.y + v.z + v.w;
    sq += v.x*v.x + v.y*v.y + v.z*v.z + v.w*v.w;
  }
  for (int off = 32; off; off >>= 1) { s += __shfl_xor(s, off); sq += __shfl_xor(sq, off); }
  __shared__ float red[8];
  int wid = tid >> 6, lane = tid & 63;
  if (lane == 0) { red[wid*2] = s; red[wid*2+1] = sq; }
  __syncthreads();
  if (tid == 0) {
    gnp[(bg*8 + chunk)*2 + 0] = red[0]+red[2]+red[4]+red[6];
    gnp[(bg*8 + chunk)*2 + 1] = red[1]+red[3]+red[5]+red[7];
  }
}

// reads x [b][c][n], writes xnT bf16 [b][n][c]
__global__ __launch_bounds__(256) void gn_apply(const float* __restrict__ x,
                                                const float* __restrict__ gw,
                                                const float* __restrict__ gb,
                                                const float* __restrict__ gnp,
                                                u16* __restrict__ xnT) {
  __shared__ float T[64][65];
  int b = blockIdx.x, c0 = blockIdx.y * 64, n0 = blockIdx.z * 64;
  int bg = b * G_ + blockIdx.y;
  float S = 0.f, SQ = 0.f;
#pragma unroll
  for (int i = 0; i < 8; ++i) { S += gnp[(bg*8+i)*2]; SQ += gnp[(bg*8+i)*2+1]; }
  float mean = S * (1.f/65536.f);
  float var  = SQ * (1.f/65536.f) - mean*mean;
  float rstd = rsqrtf(var + EPS);
  int tn = threadIdx.x & 63, tc = threadIdx.x >> 6;
#pragma unroll 4
  for (int it = 0; it < 16; ++it) {
    int cl = it*4 + tc;
    int c = c0 + cl;
    float v = x[((size_t)b*C_ + c)*N_ + n0 + tn];
    T[tn][cl] = (v - mean) * rstd * gw[c] + gb[c];
  }
  __syncthreads();
#pragma unroll
  for (int p = 0; p < 2; ++p) {
    int nl = p*32 + (threadIdx.x >> 3);
    int cs = (threadIdx.x & 7) * 8;
    s16x8 o;
#pragma unroll
    for (int j = 0; j < 8; ++j) o[j] = (short)f2b(T[nl][cs + j]);
    *reinterpret_cast<s16x8*>(&xnT[((size_t)(b*N_ + n0 + nl))*C_ + c0 + cs]) = o;
  }
}

// ---------------- weights fp32 -> bf16 ----------------
__global__ __launch_bounds__(256) void cvt_w2(const float* __restrict__ w1,
                                              const float* __restrict__ w2,
                                              u16* __restrict__ o1,
                                              u16* __restrict__ o2) {
  int i = blockIdx.x * 256 + threadIdx.x;
  const int n1 = 1536*512/4;
  if (i < n1) {
    float4 v = reinterpret_cast<const float4*>(w1)[i];
    u16x4 r = { f2b(v.x), f2b(v.y), f2b(v.z), f2b(v.w) };
    reinterpret_cast<u16x4*>(o1)[i] = r;
  } else {
    int j = i - n1;
    float4 v = reinterpret_cast<const float4*>(w2)[j];
    u16x4 r = { f2b(v.x), f2b(v.y), f2b(v.z), f2b(v.w) };
    reinterpret_cast<u16x4*>(o2)[j] = r;
  }
}

// ---------------- GEMM core (A K-contig, B^T K-contig), dbuf + T2 swizzle ----------------
// Tile BM x BN, BK=64, 4 waves in 2x2, per-wave (BM/2)x(BN/2).
// LDS slot swizzle: LDS[r][sl] holds global slot sl^(r&7); staged via pre-swizzled
// global source (rule #21), read back with the same XOR -> conflict-free ds_read_b128.
// EPI 1: bf16 out O0 [row][col], ld=N, batch strideC
// EPI 2: out[b][col][n] f32 = acc + bias[col] + residual bf16 from R (xnT [b][n][c]);
//        rows are per-batch tokens (b = blockIdx.z)
template<int BM, int BN, int EPI>
__global__ __launch_bounds__(256) void gemm(const u16* __restrict__ A,
                                            const u16* __restrict__ Bm,
                                            int M, int N, int K, int lda, int ldb,
                                            long strideA, long strideB, long strideC,
                                            const float* __restrict__ bias,
                                            void* __restrict__ O0,
                                            const void* __restrict__ R) {
  constexpr int BK = 64;
  constexpr int MI = BM / 32, NI = BN / 32;
  __shared__ u16 As[2][BM*BK];
  __shared__ u16 Bs[2][BN*BK];
  int tid = threadIdx.x, wid = tid >> 6, lane = tid & 63;
  int m0 = blockIdx.x * BM, n0 = blockIdx.y * BN;
  const u16* Ab = A + (size_t)strideA * blockIdx.z;
  const u16* Bp = Bm + (size_t)strideB * blockIdx.z;

  f32x4 acc[MI][NI] = {};
  int wm = (wid >> 1) * (BM/2), wn = (wid & 1) * (BN/2);
  int sr = lane >> 3;                 // row within 8-row chunk
  int sg = (lane & 7) ^ sr;           // pre-swizzled global k-slot

  auto stage = [&](int buf, int k0) {
#pragma unroll
    for (int t = 0; t < BM/32; ++t) {
      int chunk = wid*(BM/32) + t;
      gl2lds16(Ab + (size_t)(m0 + chunk*8 + sr)*lda + k0 + sg*8,
               (void*)(&As[buf][chunk*512]));
    }
#pragma unroll
    for (int t = 0; t < BN/32; ++t) {
      int chunk = wid*(BN/32) + t;
      gl2lds16(Bp + (size_t)(n0 + chunk*8 + sr)*ldb + k0 + sg*8,
               (void*)(&Bs[buf][chunk*512]));
    }
  };

  int KT = K / BK;
  stage(0, 0);
  __syncthreads();
  int cur = 0;
  for (int kt = 0; kt < KT; ++kt) {
    if (kt + 1 < KT) stage(cur ^ 1, (kt + 1) * BK);   // prefetch overlaps compute
#pragma unroll
    for (int ks = 0; ks < BK; ks += 32) {
      int s = (ks >> 3) + (lane >> 4);                // 16B slot index 0..7
      s16x8 af[MI], bfr[NI];
#pragma unroll
      for (int mi = 0; mi < MI; ++mi) {
        int ar = wm + mi*16 + (lane & 15);
        af[mi] = *reinterpret_cast<const s16x8*>(&As[cur][ar*64 + ((s ^ (ar & 7)) << 3)]);
      }
#pragma unroll
      for (int ni = 0; ni < NI; ++ni) {
        int br = wn + ni*16 + (lane & 15);
        bfr[ni] = *reinterpret_cast<const s16x8*>(&Bs[cur][br*64 + ((s ^ (br & 7)) << 3)]);
      }
#pragma unroll
      for (int mi = 0; mi < MI; ++mi)
#pragma unroll
        for (int ni = 0; ni < NI; ++ni)
          acc[mi][ni] = __builtin_amdgcn_mfma_f32_16x16x32_bf16(af[mi], bfr[ni], acc[mi][ni], 0, 0, 0);
    }
    __syncthreads();
    cur ^= 1;
  }

#pragma unroll
  for (int mi = 0; mi < MI; ++mi) {
#pragma unroll
    for (int ni = 0; ni < NI; ++ni) {
      int col = n0 + wn + ni*16 + (lane & 15);
      if constexpr (EPI == 2) {
        int n = m0 + wm + mi*16 + (lane >> 4)*4;     // token index within batch
        int b = blockIdx.z;
        const u16* xr = (const u16*)R + ((size_t)(b*N_ + n))*C_ + col;
        size_t idx = (size_t)b*524288 + (size_t)col*1024 + n;
        float bi = bias[col];
        float4 o;
        o.x = acc[mi][ni][0] + bi + b2f(xr[0]);
        o.y = acc[mi][ni][1] + bi + b2f(xr[512]);
        o.z = acc[mi][ni][2] + bi + b2f(xr[1024]);
        o.w = acc[mi][ni][3] + bi + b2f(xr[1536]);
        *reinterpret_cast<float4*>((float*)O0 + idx) = o;
      } else {
#pragma unroll
        for (int r = 0; r < 4; ++r) {
          int row = m0 + wm + mi*16 + (lane >> 4)*4 + r;
          ((u16*)O0)[(size_t)strideC*blockIdx.z + (size_t)row*N + col] = f2b(acc[mi][ni][r]);
        }
      }
    }
  }
}

// ---------------- qkv GEMM (128x128, 3-way split epilogue) ----------------
__global__ __launch_bounds__(256) void gemm_qkv(const u16* __restrict__ A,
                                                const u16* __restrict__ Bm,
                                                const float* __restrict__ bias,
                                                u16* __restrict__ Oq,
                                                u16* __restrict__ Ok,
                                                u16* __restrict__ Ov) {
  constexpr int BM = 128, BN = 128, BK = 64;
  const int lda = 512, ldb = 512;
  __shared__ u16 As[2][BM*BK];
  __shared__ u16 Bs[2][BN*BK];
  int tid = threadIdx.x, wid = tid >> 6, lane = tid & 63;
  int m0 = blockIdx.x * BM, n0 = blockIdx.y * BN;

  f32x4 acc[4][4] = {};
  int wm = (wid >> 1) * 64, wn = (wid & 1) * 64;
  int sr = lane >> 3;
  int sg = (lane & 7) ^ sr;

  auto stage = [&](int buf, int k0) {
#pragma unroll
    for (int t = 0; t < 4; ++t) {
      int chunk = wid*4 + t;
      gl2lds16(A + (size_t)(m0 + chunk*8 + sr)*lda + k0 + sg*8,
               (void*)(&As[buf][chunk*512]));
      gl2lds16(Bm + (size_t)(n0 + chunk*8 + sr)*ldb + k0 + sg*8,
               (void*)(&Bs[buf][chunk*512]));
    }
  };

  stage(0, 0);
  __syncthreads();
  int cur = 0;
  for (int kt = 0; kt < 8; ++kt) {
    if (kt + 1 < 8) stage(cur ^ 1, (kt + 1) * BK);
#pragma unroll
    for (int ks = 0; ks < BK; ks += 32) {
      int s = (ks >> 3) + (lane >> 4);
      s16x8 af[4], bfr[4];
#pragma unroll
      for (int mi = 0; mi < 4; ++mi) {
        int ar = wm + mi*16 + (lane & 15);
        af[mi] = *reinterpret_cast<const s16x8*>(&As[cur][ar*64 + ((s ^ (ar & 7)) << 3)]);
      }
#pragma unroll
      for (int ni = 0; ni < 4; ++ni) {
        int br = wn + ni*16 + (lane & 15);
        bfr[ni] = *reinterpret_cast<const s16x8*>(&Bs[cur][br*64 + ((s ^ (br & 7)) << 3)]);
      }
#pragma unroll
      for (int mi = 0; mi < 4; ++mi)
#pragma unroll
        for (int ni = 0; ni < 4; ++ni)
          acc[mi][ni] = __builtin_amdgcn_mfma_f32_16x16x32_bf16(af[mi], bfr[ni], acc[mi][ni], 0, 0, 0);
    }
    __syncthreads();
    cur ^= 1;
  }

  u16* Odst; int cbase;
  if (n0 < 512)       { Odst = Oq; cbase = n0; }
  else if (n0 < 1024) { Odst = Ok; cbase = n0 - 512; }
  else                { Odst = Ov; cbase = n0 - 1024; }
#pragma unroll
  for (int mi = 0; mi < 4; ++mi) {
#pragma unroll
    for (int ni = 0; ni < 4; ++ni) {
      int col = n0 + wn + ni*16 + (lane & 15);
      int c   = cbase + wn + ni*16 + (lane & 15);
      float bi = bias[col];
#pragma unroll
      for (int r = 0; r < 4; ++r) {
        int row = m0 + wm + mi*16 + (lane >> 4)*4 + r;
        Odst[(size_t)row*512 + c] = f2b(acc[mi][ni][r] + bi);
      }
    }
  }
}

// ---------------- fused: k row-softmax + transpose, v transpose ----------------
__global__ __launch_bounds__(256) void kv_transform(const u16* __restrict__ kin,
                                                    const u16* __restrict__ vin,
                                                    u16* __restrict__ kT,
                                                    u16* __restrict__ vT) {
  __shared__ u16 T[32][516];
  int b = blockIdx.x, n0 = blockIdx.y * 32;
  int wid = threadIdx.x >> 6, lane = threadIdx.x & 63;

  // ---- phase 1: k softmax + transpose
#pragma unroll
  for (int i = 0; i < 8; ++i) {
    int r = wid * 8 + i;
    const u16* p = kin + ((size_t)(b*N_ + n0 + r))*C_;
    s16x8 raw = reinterpret_cast<const s16x8*>(p)[lane];
    float v[8]; float m = -3e38f;
#pragma unroll
    for (int j = 0; j < 8; ++j) { v[j] = b2f((u16)raw[j]); m = fmaxf(m, v[j]); }
    for (int off = 32; off; off >>= 1) m = fmaxf(m, __shfl_xor(m, off));
    float s = 0.f;
#pragma unroll
    for (int j = 0; j < 8; ++j) { v[j] = __expf(v[j] - m); s += v[j]; }
    for (int off = 32; off; off >>= 1) s += __shfl_xor(s, off);
    float inv = 1.f / s;
    union { s16x8 v8; unsigned long long d[2]; } o;
#pragma unroll
    for (int j = 0; j < 8; ++j) o.v8[j] = (short)f2b(v[j] * inv);
    unsigned long long* dst = reinterpret_cast<unsigned long long*>(&T[r][lane*8]);
    dst[0] = o.d[0]; dst[1] = o.d[1];
  }
  __syncthreads();
#pragma unroll
  for (int h = 0; h < 2; ++h) {
    int c = h*256 + threadIdx.x;
    u16* dst = kT + ((size_t)(b*C_ + c))*N_ + n0;
#pragma unroll
    for (int q4 = 0; q4 < 4; ++q4) {
      s16x8 o;
#pragma unroll
      for (int j = 0; j < 8; ++j) o[j] = (short)T[q4*8 + j][c];
      reinterpret_cast<s16x8*>(dst)[q4] = o;
    }
  }
  __syncthreads();

  // ---- phase 2: v transpose
#pragma unroll
  for (int i = 0; i < 8; ++i) {
    int r = wid * 8 + i;
    const u16* p = vin + ((size_t)(b*N_ + n0 + r))*C_;
    union { s16x8 v8; unsigned long long d[2]; } o;
    o.v8 = reinterpret_cast<const s16x8*>(p)[lane];
    unsigned long long* dst = reinterpret_cast<unsigned long long*>(&T[r][lane*8]);
    dst[0] = o.d[0]; dst[1] = o.d[1];
  }
  __syncthreads();
#pragma unroll
  for (int h = 0; h < 2; ++h) {
    int c = h*256 + threadIdx.x;
    u16* dst = vT + ((size_t)(b*C_ + c))*N_ + n0;
#pragma unroll
    for (int q4 = 0; q4 < 4; ++q4) {
      s16x8 o;
#pragma unroll
      for (int j = 0; j < 8; ++j) o[j] = (short)T[q4*8 + j][c];
      reinterpret_cast<s16x8*>(dst)[q4] = o;
    }
  }
}

// ---------------- q softmax over tokens (columns) ----------------
__global__ __launch_bounds__(256) void q_softmax(const u16* __restrict__ q,
                                                 u16* __restrict__ qs) {
  int b = blockIdx.x, c0 = blockIdx.y * 32;
  int t = threadIdx.x;
  int cg = t & 3;
  int rw = t >> 2;
  const u16* base = q + (size_t)b*N_*C_ + c0 + cg*8;
  float m[8], s[8];
#pragma unroll
  for (int j = 0; j < 8; ++j) { m[j] = -3e38f; s[j] = 0.f; }
  for (int it = 0; it < 16; ++it) {
    int n = it*64 + rw;
    s16x8 raw = *reinterpret_cast<const s16x8*>(base + (size_t)n*C_);
#pragma unroll
    for (int j = 0; j < 8; ++j) {
      float v = b2f((u16)raw[j]);
      float nm = fmaxf(m[j], v);
      s[j] = s[j]*__expf(m[j] - nm) + __expf(v - nm);
      m[j] = nm;
    }
  }
  __shared__ float Mr[32][65], Sr[32][65];
#pragma unroll
  for (int j = 0; j < 8; ++j) { Mr[cg*8 + j][rw] = m[j]; Sr[cg*8 + j][rw] = s[j]; }
  __syncthreads();
  __shared__ float MS[32][2];
  if (t < 32) {
    float M = -3e38f;
    for (int i = 0; i < 64; ++i) M = fmaxf(M, Mr[t][i]);
    float S = 0.f;
    for (int i = 0; i < 64; ++i) S += Sr[t][i]*__expf(Mr[t][i] - M);
    MS[t][0] = M; MS[t][1] = 1.f / S;
  }
  __syncthreads();
  float Mv[8], Iv[8];
#pragma unroll
  for (int j = 0; j < 8; ++j) { Mv[j] = MS[cg*8 + j][0]; Iv[j] = MS[cg*8 + j][1]; }
  u16* ob = qs + (size_t)b*N_*C_ + c0 + cg*8;
  for (int it = 0; it < 16; ++it) {
    int n = it*64 + rw;
    s16x8 raw = *reinterpret_cast<const s16x8*>(base + (size_t)n*C_);
    s16x8 o;
#pragma unroll
    for (int j = 0; j < 8; ++j)
      o[j] = (short)f2b(__expf(b2f((u16)raw[j]) - Mv[j]) * Iv[j]);
    *reinterpret_cast<s16x8*>(ob + (size_t)n*C_) = o;
  }
}

// ---------------- launch ----------------
extern "C" void kernel_launch(void* const* d_in, const int* in_sizes, int n_in,
                              void* d_out, int out_size, void* d_ws, size_t ws_size,
                              hipStream_t stream) {
  (void)in_sizes; (void)n_in; (void)out_size; (void)ws_size;
  const float* x      = (const float*)d_in[0];
  const float* gn_w   = (const float*)d_in[1];
  const float* gn_b   = (const float*)d_in[2];
  const float* qkv_w  = (const float*)d_in[3];
  const float* qkv_b  = (const float*)d_in[4];
  const float* proj_w = (const float*)d_in[5];
  const float* proj_b = (const float*)d_in[6];

  char* ws = (char*)d_ws;
  u16*   xnT  = (u16*)  (ws + OFF_XNT);
  u16*   qb   = (u16*)  (ws + OFF_Q);
  u16*   kb   = (u16*)  (ws + OFF_K);
  u16*   vb   = (u16*)  (ws + OFF_V);
  u16*   kT   = (u16*)  (ws + OFF_KT);
  u16*   vT   = (u16*)  (ws + OFF_VT);
  u16*   qsb  = (u16*)  (ws + OFF_QS);
  u16*   ctx  = (u16*)  (ws + OFF_CTX);
  u16*   mt   = (u16*)  (ws + OFF_MT);
  u16*   wq   = (u16*)  (ws + OFF_WQ);
  u16*   wp   = (u16*)  (ws + OFF_WP);
  float* gnp  = (float*)(ws + OFF_GNP);

  gn_partial<<<dim3(64, 8), 256, 0, stream>>>(x, gnp);
  gn_apply<<<dim3(8, 8, 16), 256, 0, stream>>>(x, gn_w, gn_b, gnp, xnT);

  cvt_w2<<<dim3(1024), 256, 0, stream>>>(qkv_w, proj_w, wq, wp);

  // qkv: [8192,512] x [1536,512]^T -> q,k,v bf16 [tok][c]
  gemm_qkv<<<dim3(64, 12), 256, 0, stream>>>(xnT, wq, qkv_b, qb, kb, vb);

  kv_transform<<<dim3(8, 32), 256, 0, stream>>>(kb, vb, kT, vT);
  q_softmax<<<dim3(8, 16), 256, 0, stream>>>(qb, qsb);

  // ctx[b][c][d] = sum_n kT[b][c][n] * vT[b][d][n]
  gemm<64,64,1><<<dim3(8, 8, 8), 256, 0, stream>>>(kT, vT, 512, 512, 1024, 1024, 1024,
                                                   524288, 524288, 262144, nullptr, ctx, nullptr);
  // MT[b][e][c] = sum_d wp[e][d] * ctx[b][c][d]   ( = (ctx @ wp^T)^T )
  gemm<64,64,1><<<dim3(8, 8, 8), 256, 0, stream>>>(wp, ctx, 512, 512, 512, 512, 512,
                                                   0, 262144, 262144, nullptr, mt, nullptr);
  // out[b][e][n] = sum_c qs[b][n][c] * MT[b][e][c] + proj_b[e] + xn  (fused att+proj)
  gemm<64,64,2><<<dim3(16, 8, 8), 256, 0, stream>>>(qsb, mt, 1024, 512, 512, 512, 512,
                                                    524288, 262144, 0, proj_b, (float*)d_out, xnT);
}

// Round 6
// 163.148 us; speedup vs baseline: 1.3288x; 1.0555x over previous
//
#include <hip/hip_runtime.h>
#include <hip/hip_bf16.h>
#include <stdint.h>

typedef unsigned short u16;
typedef __attribute__((ext_vector_type(8))) short s16x8;
typedef __attribute__((ext_vector_type(4))) float f32x4;
typedef __attribute__((ext_vector_type(4))) unsigned short u16x4;

static constexpr int B_ = 8, C_ = 512, N_ = 1024, G_ = 8;
static constexpr float EPS = 1e-5f;

// ---------------- workspace layout (bytes) ----------------
static constexpr size_t OFF_XNT  = 0;                                   // bf16 [B][N][C] groupnorm out
static constexpr size_t OFF_Q    = OFF_XNT  + (size_t)B_*N_*C_*2;       // bf16 [B][N][C] q raw
static constexpr size_t OFF_K    = OFF_Q    + (size_t)B_*N_*C_*2;       // bf16 [B][N][C] k raw
static constexpr size_t OFF_V    = OFF_K    + (size_t)B_*N_*C_*2;       // bf16 [B][N][C] v raw
static constexpr size_t OFF_KT   = OFF_V    + (size_t)B_*N_*C_*2;       // bf16 [B][C][N] softmax(k)^T
static constexpr size_t OFF_VT   = OFF_KT   + (size_t)B_*N_*C_*2;       // bf16 [B][C][N] v^T
static constexpr size_t OFF_QS   = OFF_VT   + (size_t)B_*N_*C_*2;       // bf16 [B][N][C] softmax(q)
static constexpr size_t OFF_CTX  = OFF_QS   + (size_t)B_*N_*C_*2;       // bf16 [B][C][C] ctx [c][d]
static constexpr size_t OFF_MT   = OFF_CTX  + (size_t)B_*C_*C_*2;       // bf16 [B][C][C] (ctx@wp^T)^T : [e][c]
static constexpr size_t OFF_WQ   = OFF_MT   + (size_t)B_*C_*C_*2;       // bf16 [1536][512]
static constexpr size_t OFF_WP   = OFF_WQ   + (size_t)3*C_*C_*2;        // bf16 [512][512]
static constexpr size_t OFF_GNP  = OFF_WP   + (size_t)C_*C_*2;          // f32 [64][8][2]

// ---------------- helpers ----------------
__device__ __forceinline__ float b2f(u16 u) {
  union { float f; uint32_t i; } x; x.i = ((uint32_t)u) << 16; return x.f;
}
__device__ __forceinline__ u16 f2b(float f) {
  union { float f; uint32_t i; } x; x.f = f;
  return (u16)((x.i + 0x7fffu + ((x.i >> 16) & 1u)) >> 16);
}
#define AS1 __attribute__((address_space(1)))
#define AS3 __attribute__((address_space(3)))
__device__ __forceinline__ void gl2lds16(const void* g, void* l) {
  __builtin_amdgcn_global_load_lds((const AS1 void*)g, (AS3 void*)l, 16, 0, 0);
}

// ---------------- pre: groupnorm partial sums + weight conversion ----------------
__global__ __launch_bounds__(256) void pre_kernel(const float* __restrict__ x,
                                                  float* __restrict__ gnp,
                                                  const float* __restrict__ w1,
                                                  const float* __restrict__ w2,
                                                  u16* __restrict__ o1,
                                                  u16* __restrict__ o2) {
  int bid = blockIdx.x;
  if (bid < 512) {
    // groupnorm partial: bg = bid>>3, chunk = bid&7
    int bg = bid >> 3, chunk = bid & 7;
    const float4* p = reinterpret_cast<const float4*>(x + (size_t)bg * 65536 + (size_t)chunk * 8192);
    int tid = threadIdx.x;
    float s = 0.f, sq = 0.f;
#pragma unroll
    for (int i = 0; i < 8; ++i) {
      float4 v = p[i * 256 + tid];
      s  += v.x + v.y + v.z + v.w;
      sq += v.x*v.x + v.y*v.y + v.z*v.z + v.w*v.w;
    }
    for (int off = 32; off; off >>= 1) { s += __shfl_xor(s, off); sq += __shfl_xor(sq, off); }
    __shared__ float red[8];
    int wid = tid >> 6, lane = tid & 63;
    if (lane == 0) { red[wid*2] = s; red[wid*2+1] = sq; }
    __syncthreads();
    if (tid == 0) {
      gnp[(bg*8 + chunk)*2 + 0] = red[0]+red[2]+red[4]+red[6];
      gnp[(bg*8 + chunk)*2 + 1] = red[1]+red[3]+red[5]+red[7];
    }
  } else {
    // weight fp32->bf16: 1024 blocks
    int i = (bid - 512) * 256 + threadIdx.x;
    const int n1 = 1536*512/4;
    if (i < n1) {
      float4 v = reinterpret_cast<const float4*>(w1)[i];
      u16x4 r = { f2b(v.x), f2b(v.y), f2b(v.z), f2b(v.w) };
      reinterpret_cast<u16x4*>(o1)[i] = r;
    } else {
      int j = i - n1;
      float4 v = reinterpret_cast<const float4*>(w2)[j];
      u16x4 r = { f2b(v.x), f2b(v.y), f2b(v.z), f2b(v.w) };
      reinterpret_cast<u16x4*>(o2)[j] = r;
    }
  }
}

// reads x [b][c][n], writes xnT bf16 [b][n][c]
__global__ __launch_bounds__(256) void gn_apply(const float* __restrict__ x,
                                                const float* __restrict__ gw,
                                                const float* __restrict__ gb,
                                                const float* __restrict__ gnp,
                                                u16* __restrict__ xnT) {
  __shared__ float T[64][65];
  int b = blockIdx.x, c0 = blockIdx.y * 64, n0 = blockIdx.z * 64;
  int bg = b * G_ + blockIdx.y;
  float S = 0.f, SQ = 0.f;
#pragma unroll
  for (int i = 0; i < 8; ++i) { S += gnp[(bg*8+i)*2]; SQ += gnp[(bg*8+i)*2+1]; }
  float mean = S * (1.f/65536.f);
  float var  = SQ * (1.f/65536.f) - mean*mean;
  float rstd = rsqrtf(var + EPS);
  int tn = threadIdx.x & 63, tc = threadIdx.x >> 6;
#pragma unroll 4
  for (int it = 0; it < 16; ++it) {
    int cl = it*4 + tc;
    int c = c0 + cl;
    float v = x[((size_t)b*C_ + c)*N_ + n0 + tn];
    T[tn][cl] = (v - mean) * rstd * gw[c] + gb[c];
  }
  __syncthreads();
#pragma unroll
  for (int p = 0; p < 2; ++p) {
    int nl = p*32 + (threadIdx.x >> 3);
    int cs = (threadIdx.x & 7) * 8;
    s16x8 o;
#pragma unroll
    for (int j = 0; j < 8; ++j) o[j] = (short)f2b(T[nl][cs + j]);
    *reinterpret_cast<s16x8*>(&xnT[((size_t)(b*N_ + n0 + nl))*C_ + c0 + cs]) = o;
  }
}

// ---------------- qkv GEMM: 256x256 tile, 8 waves, counted-vmcnt schedule ----------------
// A = xnT [8192][512] K-contig; B = wq [1536][512] K-contig (B^T form).
// LDS: 2 x (256x64) for A and B = 128 KB. Slot swizzle slot^(row&7), staged via
// pre-swizzled global source (linear LDS dest), read back with the same XOR.
// Main loop NEVER drains vmcnt to 0: stage(t+1); vmcnt(8); s_barrier;
// 4 quadrant sub-phases {12 ds_read_b128, setprio(1), 16 MFMA, setprio(0)};
// lgkmcnt(0); s_barrier.
__global__ __launch_bounds__(512, 2) void gemm_qkv8(const u16* __restrict__ A,
                                                    const u16* __restrict__ Bm,
                                                    const float* __restrict__ bias,
                                                    u16* __restrict__ Oq,
                                                    u16* __restrict__ Ok,
                                                    u16* __restrict__ Ov) {
  const int lda = 512, ldb = 512;
  __shared__ u16 As[2][256*64];
  __shared__ u16 Bs[2][256*64];
  int tid = threadIdx.x, wid = tid >> 6, lane = tid & 63;
  int wr = wid >> 2, wc = wid & 3;           // 2M x 4N wave grid
  int m0 = blockIdx.x * 256, n0 = blockIdx.y * 256;

  f32x4 acc[8][4] = {};
  int sr = lane >> 3;                        // row within 8-row chunk
  int sg = (lane & 7) ^ sr;                  // pre-swizzled global k-slot

  auto stage = [&](int buf, int k0) {
#pragma unroll
    for (int t = 0; t < 4; ++t) {
      int chunk = wid*4 + t;                 // 0..31 (8 rows each, 256 rows total)
      gl2lds16(A  + (size_t)(m0 + chunk*8 + sr)*lda + k0 + sg*8,
               (void*)(&As[buf][chunk*512]));
      gl2lds16(Bm + (size_t)(n0 + chunk*8 + sr)*ldb + k0 + sg*8,
               (void*)(&Bs[buf][chunk*512]));
    }
  };  // 8 gl2lds per wave per tile

  stage(0, 0);
  int cur = 0;
  for (int kt = 0; kt < 8; ++kt) {
    if (kt + 1 < 8) {
      stage(cur ^ 1, (kt + 1) * 64);
      asm volatile("s_waitcnt vmcnt(8)" ::: "memory");   // tile kt landed; t+1 stays in flight
    } else {
      asm volatile("s_waitcnt vmcnt(0)" ::: "memory");
    }
    __builtin_amdgcn_s_barrier();
    __builtin_amdgcn_sched_barrier(0);

#pragma unroll
    for (int q = 0; q < 4; ++q) {            // quadrant: qa = A 64-row half, qb = B 32-col half
      const int qa = q >> 1, qb = q & 1;
      s16x8 af[4][2], bfq[2][2];
#pragma unroll
      for (int mi2 = 0; mi2 < 4; ++mi2)
#pragma unroll
        for (int ks2 = 0; ks2 < 2; ++ks2) {
          int ar = wr*128 + qa*64 + mi2*16 + (lane & 15);
          int s  = ks2*4 + (lane >> 4);
          af[mi2][ks2] = *reinterpret_cast<const s16x8*>(&As[cur][ar*64 + ((s ^ (ar & 7)) << 3)]);
        }
#pragma unroll
      for (int ni2 = 0; ni2 < 2; ++ni2)
#pragma unroll
        for (int ks2 = 0; ks2 < 2; ++ks2) {
          int br = wc*64 + qb*32 + ni2*16 + (lane & 15);
          int s  = ks2*4 + (lane >> 4);
          bfq[ni2][ks2] = *reinterpret_cast<const s16x8*>(&Bs[cur][br*64 + ((s ^ (br & 7)) << 3)]);
        }
      __builtin_amdgcn_s_setprio(1);
#pragma unroll
      for (int mi2 = 0; mi2 < 4; ++mi2)
#pragma unroll
        for (int ni2 = 0; ni2 < 2; ++ni2)
#pragma unroll
          for (int ks2 = 0; ks2 < 2; ++ks2)
            acc[qa*4 + mi2][qb*2 + ni2] =
              __builtin_amdgcn_mfma_f32_16x16x32_bf16(af[mi2][ks2], bfq[ni2][ks2],
                                                      acc[qa*4 + mi2][qb*2 + ni2], 0, 0, 0);
      __builtin_amdgcn_s_setprio(0);
    }

    asm volatile("s_waitcnt lgkmcnt(0)" ::: "memory");   // LDS reads of buf done
    __builtin_amdgcn_s_barrier();                        // before next stage overwrites buf
    __builtin_amdgcn_sched_barrier(0);
    cur ^= 1;
  }

  // epilogue: 256-col tile lies entirely within one of q/k/v (512-wide segments)
  u16* Odst; int cbase;
  if (n0 < 512)       { Odst = Oq; cbase = n0; }
  else if (n0 < 1024) { Odst = Ok; cbase = n0 - 512; }
  else                { Odst = Ov; cbase = n0 - 1024; }
#pragma unroll
  for (int mi = 0; mi < 8; ++mi) {
#pragma unroll
    for (int ni = 0; ni < 4; ++ni) {
      int cseg = cbase + wc*64 + ni*16 + (lane & 15);
      float bi = bias[n0 + wc*64 + ni*16 + (lane & 15)];
#pragma unroll
      for (int r = 0; r < 4; ++r) {
        int row = m0 + wr*128 + mi*16 + (lane >> 4)*4 + r;
        Odst[(size_t)row*512 + cseg] = f2b(acc[mi][ni][r] + bi);
      }
    }
  }
}

// ---------------- GEMM core (A K-contig, B^T K-contig), dbuf + swizzle ----------------
// EPI 1: bf16 out O0 [row][col], ld=N, batch strideC
// EPI 2: out[b][col][n] f32 = acc + bias[col] + residual bf16 from R (xnT [b][n][c])
template<int BM, int BN, int EPI>
__global__ __launch_bounds__(256) void gemm(const u16* __restrict__ A,
                                            const u16* __restrict__ Bm,
                                            int M, int N, int K, int lda, int ldb,
                                            long strideA, long strideB, long strideC,
                                            const float* __restrict__ bias,
                                            void* __restrict__ O0,
                                            const void* __restrict__ R) {
  constexpr int BK = 64;
  constexpr int MI = BM / 32, NI = BN / 32;
  __shared__ u16 As[2][BM*BK];
  __shared__ u16 Bs[2][BN*BK];
  int tid = threadIdx.x, wid = tid >> 6, lane = tid & 63;
  int m0 = blockIdx.x * BM, n0 = blockIdx.y * BN;
  const u16* Ab = A + (size_t)strideA * blockIdx.z;
  const u16* Bp = Bm + (size_t)strideB * blockIdx.z;

  f32x4 acc[MI][NI] = {};
  int wm = (wid >> 1) * (BM/2), wn = (wid & 1) * (BN/2);
  int sr = lane >> 3;
  int sg = (lane & 7) ^ sr;

  auto stage = [&](int buf, int k0) {
#pragma unroll
    for (int t = 0; t < BM/32; ++t) {
      int chunk = wid*(BM/32) + t;
      gl2lds16(Ab + (size_t)(m0 + chunk*8 + sr)*lda + k0 + sg*8,
               (void*)(&As[buf][chunk*512]));
    }
#pragma unroll
    for (int t = 0; t < BN/32; ++t) {
      int chunk = wid*(BN/32) + t;
      gl2lds16(Bp + (size_t)(n0 + chunk*8 + sr)*ldb + k0 + sg*8,
               (void*)(&Bs[buf][chunk*512]));
    }
  };

  int KT = K / BK;
  stage(0, 0);
  __syncthreads();
  int cur = 0;
  for (int kt = 0; kt < KT; ++kt) {
    if (kt + 1 < KT) stage(cur ^ 1, (kt + 1) * BK);
#pragma unroll
    for (int ks = 0; ks < BK; ks += 32) {
      int s = (ks >> 3) + (lane >> 4);
      s16x8 af[MI], bfr[NI];
#pragma unroll
      for (int mi = 0; mi < MI; ++mi) {
        int ar = wm + mi*16 + (lane & 15);
        af[mi] = *reinterpret_cast<const s16x8*>(&As[cur][ar*64 + ((s ^ (ar & 7)) << 3)]);
      }
#pragma unroll
      for (int ni = 0; ni < NI; ++ni) {
        int br = wn + ni*16 + (lane & 15);
        bfr[ni] = *reinterpret_cast<const s16x8*>(&Bs[cur][br*64 + ((s ^ (br & 7)) << 3)]);
      }
#pragma unroll
      for (int mi = 0; mi < MI; ++mi)
#pragma unroll
        for (int ni = 0; ni < NI; ++ni)
          acc[mi][ni] = __builtin_amdgcn_mfma_f32_16x16x32_bf16(af[mi], bfr[ni], acc[mi][ni], 0, 0, 0);
    }
    __syncthreads();
    cur ^= 1;
  }

#pragma unroll
  for (int mi = 0; mi < MI; ++mi) {
#pragma unroll
    for (int ni = 0; ni < NI; ++ni) {
      int col = n0 + wn + ni*16 + (lane & 15);
      if constexpr (EPI == 2) {
        int n = m0 + wm + mi*16 + (lane >> 4)*4;
        int b = blockIdx.z;
        const u16* xr = (const u16*)R + ((size_t)(b*N_ + n))*C_ + col;
        size_t idx = (size_t)b*524288 + (size_t)col*1024 + n;
        float bi = bias[col];
        float4 o;
        o.x = acc[mi][ni][0] + bi + b2f(xr[0]);
        o.y = acc[mi][ni][1] + bi + b2f(xr[512]);
        o.z = acc[mi][ni][2] + bi + b2f(xr[1024]);
        o.w = acc[mi][ni][3] + bi + b2f(xr[1536]);
        *reinterpret_cast<float4*>((float*)O0 + idx) = o;
      } else {
#pragma unroll
        for (int r = 0; r < 4; ++r) {
          int row = m0 + wm + mi*16 + (lane >> 4)*4 + r;
          ((u16*)O0)[(size_t)strideC*blockIdx.z + (size_t)row*N + col] = f2b(acc[mi][ni][r]);
        }
      }
    }
  }
}

// ---------------- mid: k softmax+transpose, v transpose, q softmax ----------------
__global__ __launch_bounds__(256) void mid_kernel(const u16* __restrict__ kin,
                                                  const u16* __restrict__ vin,
                                                  u16* __restrict__ kT,
                                                  u16* __restrict__ vT,
                                                  const u16* __restrict__ q,
                                                  u16* __restrict__ qs) {
  __shared__ __align__(16) char smem[33024];
  int bid = blockIdx.x;
  if (bid < 256) {
    // ---- kv transform: b = bid>>5, n0 = (bid&31)*32
    u16 (*T)[516] = (u16(*)[516])smem;
    int b = bid >> 5, n0 = (bid & 31) * 32;
    int wid = threadIdx.x >> 6, lane = threadIdx.x & 63;

    // phase 1: k softmax + transpose
#pragma unroll
    for (int i = 0; i < 8; ++i) {
      int r = wid * 8 + i;
      const u16* p = kin + ((size_t)(b*N_ + n0 + r))*C_;
      s16x8 raw = reinterpret_cast<const s16x8*>(p)[lane];
      float v[8]; float m = -3e38f;
#pragma unroll
      for (int j = 0; j < 8; ++j) { v[j] = b2f((u16)raw[j]); m = fmaxf(m, v[j]); }
      for (int off = 32; off; off >>= 1) m = fmaxf(m, __shfl_xor(m, off));
      float s = 0.f;
#pragma unroll
      for (int j = 0; j < 8; ++j) { v[j] = __expf(v[j] - m); s += v[j]; }
      for (int off = 32; off; off >>= 1) s += __shfl_xor(s, off);
      float inv = 1.f / s;
      union { s16x8 v8; unsigned long long d[2]; } o;
#pragma unroll
      for (int j = 0; j < 8; ++j) o.v8[j] = (short)f2b(v[j] * inv);
      unsigned long long* dst = reinterpret_cast<unsigned long long*>(&T[r][lane*8]);
      dst[0] = o.d[0]; dst[1] = o.d[1];
    }
    __syncthreads();
#pragma unroll
    for (int h = 0; h < 2; ++h) {
      int c = h*256 + threadIdx.x;
      u16* dst = kT + ((size_t)(b*C_ + c))*N_ + n0;
#pragma unroll
      for (int q4 = 0; q4 < 4; ++q4) {
        s16x8 o;
#pragma unroll
        for (int j = 0; j < 8; ++j) o[j] = (short)T[q4*8 + j][c];
        reinterpret_cast<s16x8*>(dst)[q4] = o;
      }
    }
    __syncthreads();

    // phase 2: v transpose
#pragma unroll
    for (int i = 0; i < 8; ++i) {
      int r = wid * 8 + i;
      const u16* p = vin + ((size_t)(b*N_ + n0 + r))*C_;
      union { s16x8 v8; unsigned long long d[2]; } o;
      o.v8 = reinterpret_cast<const s16x8*>(p)[lane];
      unsigned long long* dst = reinterpret_cast<unsigned long long*>(&T[r][lane*8]);
      dst[0] = o.d[0]; dst[1] = o.d[1];
    }
    __syncthreads();
#pragma unroll
    for (int h = 0; h < 2; ++h) {
      int c = h*256 + threadIdx.x;
      u16* dst = vT + ((size_t)(b*C_ + c))*N_ + n0;
#pragma unroll
      for (int q4 = 0; q4 < 4; ++q4) {
        s16x8 o;
#pragma unroll
        for (int j = 0; j < 8; ++j) o[j] = (short)T[q4*8 + j][c];
        reinterpret_cast<s16x8*>(dst)[q4] = o;
      }
    }
  } else {
    // ---- q softmax over tokens: j = bid-256; b = j>>4, c0 = (j&15)*32
    float (*Mr)[65] = (float(*)[65])smem;
    float (*Sr)[65] = (float(*)[65])(smem + 8320);
    float (*MS)[2]  = (float(*)[2]) (smem + 16640);
    int j2 = bid - 256;
    int b = j2 >> 4, c0 = (j2 & 15) * 32;
    int t = threadIdx.x;
    int cg = t & 3;
    int rw = t >> 2;
    const u16* base = q + (size_t)b*N_*C_ + c0 + cg*8;
    float m[8], s[8];
#pragma unroll
    for (int j = 0; j < 8; ++j) { m[j] = -3e38f; s[j] = 0.f; }
    for (int it = 0; it < 16; ++it) {
      int n = it*64 + rw;
      s16x8 raw = *reinterpret_cast<const s16x8*>(base + (size_t)n*C_);
#pragma unroll
      for (int j = 0; j < 8; ++j) {
        float v = b2f((u16)raw[j]);
        float nm = fmaxf(m[j], v);
        s[j] = s[j]*__expf(m[j] - nm) + __expf(v - nm);
        m[j] = nm;
      }
    }
#pragma unroll
    for (int j = 0; j < 8; ++j) { Mr[cg*8 + j][rw] = m[j]; Sr[cg*8 + j][rw] = s[j]; }
    __syncthreads();
    if (t < 32) {
      float M = -3e38f;
      for (int i = 0; i < 64; ++i) M = fmaxf(M, Mr[t][i]);
      float S = 0.f;
      for (int i = 0; i < 64; ++i) S += Sr[t][i]*__expf(Mr[t][i] - M);
      MS[t][0] = M; MS[t][1] = 1.f / S;
    }
    __syncthreads();
    float Mv[8], Iv[8];
#pragma unroll
    for (int j = 0; j < 8; ++j) { Mv[j] = MS[cg*8 + j][0]; Iv[j] = MS[cg*8 + j][1]; }
    u16* ob = qs + (size_t)b*N_*C_ + c0 + cg*8;
    for (int it = 0; it < 16; ++it) {
      int n = it*64 + rw;
      s16x8 raw = *reinterpret_cast<const s16x8*>(base + (size_t)n*C_);
      s16x8 o;
#pragma unroll
      for (int j = 0; j < 8; ++j)
        o[j] = (short)f2b(__expf(b2f((u16)raw[j]) - Mv[j]) * Iv[j]);
      *reinterpret_cast<s16x8*>(ob + (size_t)n*C_) = o;
    }
  }
}

// ---------------- launch ----------------
extern "C" void kernel_launch(void* const* d_in, const int* in_sizes, int n_in,
                              void* d_out, int out_size, void* d_ws, size_t ws_size,
                              hipStream_t stream) {
  (void)in_sizes; (void)n_in; (void)out_size; (void)ws_size;
  const float* x      = (const float*)d_in[0];
  const float* gn_w   = (const float*)d_in[1];
  const float* gn_b   = (const float*)d_in[2];
  const float* qkv_w  = (const float*)d_in[3];
  const float* qkv_b  = (const float*)d_in[4];
  const float* proj_w = (const float*)d_in[5];
  const float* proj_b = (const float*)d_in[6];

  char* ws = (char*)d_ws;
  u16*   xnT  = (u16*)  (ws + OFF_XNT);
  u16*   qb   = (u16*)  (ws + OFF_Q);
  u16*   kb   = (u16*)  (ws + OFF_K);
  u16*   vb   = (u16*)  (ws + OFF_V);
  u16*   kT   = (u16*)  (ws + OFF_KT);
  u16*   vT   = (u16*)  (ws + OFF_VT);
  u16*   qsb  = (u16*)  (ws + OFF_QS);
  u16*   ctx  = (u16*)  (ws + OFF_CTX);
  u16*   mt   = (u16*)  (ws + OFF_MT);
  u16*   wq   = (u16*)  (ws + OFF_WQ);
  u16*   wp   = (u16*)  (ws + OFF_WP);
  float* gnp  = (float*)(ws + OFF_GNP);

  // groupnorm partials + weight cvt (one node)
  pre_kernel<<<dim3(1536), 256, 0, stream>>>(x, gnp, qkv_w, proj_w, wq, wp);
  gn_apply<<<dim3(8, 8, 16), 256, 0, stream>>>(x, gn_w, gn_b, gnp, xnT);

  // qkv: [8192,512] x [1536,512]^T -> q,k,v bf16 [tok][c]; 256^2 counted-vmcnt schedule
  gemm_qkv8<<<dim3(32, 6), 512, 0, stream>>>(xnT, wq, qkv_b, qb, kb, vb);

  // k softmax+T, v T, q softmax (one node)
  mid_kernel<<<dim3(384), 256, 0, stream>>>(kb, vb, kT, vT, qb, qsb);

  // ctx[b][c][d] = sum_n kT[b][c][n] * vT[b][d][n]
  gemm<64,64,1><<<dim3(8, 8, 8), 256, 0, stream>>>(kT, vT, 512, 512, 1024, 1024, 1024,
                                                   524288, 524288, 262144, nullptr, ctx, nullptr);
  // MT[b][e][c] = sum_d wp[e][d] * ctx[b][c][d]   ( = (ctx @ wp^T)^T )
  gemm<64,64,1><<<dim3(8, 8, 8), 256, 0, stream>>>(wp, ctx, 512, 512, 512, 512, 512,
                                                   0, 262144, 262144, nullptr, mt, nullptr);
  // out[b][e][n] = sum_c qs[b][n][c] * MT[b][e][c] + proj_b[e] + xn  (fused att+proj)
  gemm<64,64,2><<<dim3(16, 8, 8), 256, 0, stream>>>(qsb, mt, 1024, 512, 512, 512, 512,
                                                    524288, 262144, 0, proj_b, (float*)d_out, xnT);
}

// Round 11
// 155.146 us; speedup vs baseline: 1.3974x; 1.0516x over previous
//
#include <hip/hip_runtime.h>
#include <hip/hip_bf16.h>
#include <stdint.h>

typedef unsigned short u16;
typedef __attribute__((ext_vector_type(8))) short s16x8;
typedef __attribute__((ext_vector_type(4))) float f32x4;
typedef __attribute__((ext_vector_type(4))) unsigned short u16x4;

static constexpr int B_ = 8, C_ = 512, N_ = 1024, G_ = 8;
static constexpr float EPS = 1e-5f;

// ---------------- workspace layout (bytes) ----------------
static constexpr size_t OFF_XNT  = 0;                                   // bf16 [B][N][C] groupnorm out
static constexpr size_t OFF_Q    = OFF_XNT  + (size_t)B_*N_*C_*2;       // bf16 [B][N][C] q raw
static constexpr size_t OFF_K    = OFF_Q    + (size_t)B_*N_*C_*2;       // bf16 [B][N][C] k raw
static constexpr size_t OFF_KT   = OFF_K    + (size_t)B_*N_*C_*2;       // bf16 [B][C][N] softmax(k)^T
static constexpr size_t OFF_VT   = OFF_KT   + (size_t)B_*N_*C_*2;       // bf16 [B][C][N] v^T (written by qkv8)
static constexpr size_t OFF_QS   = OFF_VT   + (size_t)B_*N_*C_*2;       // bf16 [B][N][C] softmax(q)
static constexpr size_t OFF_CTX  = OFF_QS   + (size_t)B_*N_*C_*2;       // bf16 [B][C][C] ctx [c][d]
static constexpr size_t OFF_MT   = OFF_CTX  + (size_t)B_*C_*C_*2;       // bf16 [B][C][C] (ctx@wp^T)^T : [e][c]
static constexpr size_t OFF_WQ   = OFF_MT   + (size_t)B_*C_*C_*2;       // bf16 [1536][512]
static constexpr size_t OFF_WP   = OFF_WQ   + (size_t)3*C_*C_*2;        // bf16 [512][512]
static constexpr size_t OFF_GNP  = OFF_WP   + (size_t)C_*C_*2;          // f32 [64][8][2]

// ---------------- helpers ----------------
__device__ __forceinline__ float b2f(u16 u) {
  union { float f; uint32_t i; } x; x.i = ((uint32_t)u) << 16; return x.f;
}
__device__ __forceinline__ u16 f2b(float f) {
  union { float f; uint32_t i; } x; x.f = f;
  return (u16)((x.i + 0x7fffu + ((x.i >> 16) & 1u)) >> 16);
}
#define AS1 __attribute__((address_space(1)))
#define AS3 __attribute__((address_space(3)))
__device__ __forceinline__ void gl2lds16(const void* g, void* l) {
  __builtin_amdgcn_global_load_lds((const AS1 void*)g, (AS3 void*)l, 16, 0, 0);
}

// ---------------- pre: groupnorm partial sums + weight conversion ----------------
__global__ __launch_bounds__(256) void pre_kernel(const float* __restrict__ x,
                                                  float* __restrict__ gnp,
                                                  const float* __restrict__ w1,
                                                  const float* __restrict__ w2,
                                                  u16* __restrict__ o1,
                                                  u16* __restrict__ o2) {
  int bid = blockIdx.x;
  if (bid < 512) {
    int bg = bid >> 3, chunk = bid & 7;
    const float4* p = reinterpret_cast<const float4*>(x + (size_t)bg * 65536 + (size_t)chunk * 8192);
    int tid = threadIdx.x;
    float s = 0.f, sq = 0.f;
#pragma unroll
    for (int i = 0; i < 8; ++i) {
      float4 v = p[i * 256 + tid];
      s  += v.x + v.y + v.z + v.w;
      sq += v.x*v.x + v.y*v.y + v.z*v.z + v.w*v.w;
    }
    for (int off = 32; off; off >>= 1) { s += __shfl_xor(s, off); sq += __shfl_xor(sq, off); }
    __shared__ float red[8];
    int wid = tid >> 6, lane = tid & 63;
    if (lane == 0) { red[wid*2] = s; red[wid*2+1] = sq; }
    __syncthreads();
    if (tid == 0) {
      gnp[(bg*8 + chunk)*2 + 0] = red[0]+red[2]+red[4]+red[6];
      gnp[(bg*8 + chunk)*2 + 1] = red[1]+red[3]+red[5]+red[7];
    }
  } else {
    int i = (bid - 512) * 256 + threadIdx.x;
    const int n1 = 1536*512/4;
    if (i < n1) {
      float4 v = reinterpret_cast<const float4*>(w1)[i];
      u16x4 r = { f2b(v.x), f2b(v.y), f2b(v.z), f2b(v.w) };
      reinterpret_cast<u16x4*>(o1)[i] = r;
    } else {
      int j = i - n1;
      float4 v = reinterpret_cast<const float4*>(w2)[j];
      u16x4 r = { f2b(v.x), f2b(v.y), f2b(v.z), f2b(v.w) };
      reinterpret_cast<u16x4*>(o2)[j] = r;
    }
  }
}

// reads x [b][c][n], writes xnT bf16 [b][n][c]
__global__ __launch_bounds__(256) void gn_apply(const float* __restrict__ x,
                                                const float* __restrict__ gw,
                                                const float* __restrict__ gb,
                                                const float* __restrict__ gnp,
                                                u16* __restrict__ xnT) {
  __shared__ float T[64][65];
  int b = blockIdx.x, c0 = blockIdx.y * 64, n0 = blockIdx.z * 64;
  int bg = b * G_ + blockIdx.y;
  float S = 0.f, SQ = 0.f;
#pragma unroll
  for (int i = 0; i < 8; ++i) { S += gnp[(bg*8+i)*2]; SQ += gnp[(bg*8+i)*2+1]; }
  float mean = S * (1.f/65536.f);
  float var  = SQ * (1.f/65536.f) - mean*mean;
  float rstd = rsqrtf(var + EPS);
  int tn = threadIdx.x & 63, tc = threadIdx.x >> 6;
#pragma unroll 4
  for (int it = 0; it < 16; ++it) {
    int cl = it*4 + tc;
    int c = c0 + cl;
    float v = x[((size_t)b*C_ + c)*N_ + n0 + tn];
    T[tn][cl] = (v - mean) * rstd * gw[c] + gb[c];
  }
  __syncthreads();
#pragma unroll
  for (int p = 0; p < 2; ++p) {
    int nl = p*32 + (threadIdx.x >> 3);
    int cs = (threadIdx.x & 7) * 8;
    s16x8 o;
#pragma unroll
    for (int j = 0; j < 8; ++j) o[j] = (short)f2b(T[nl][cs + j]);
    *reinterpret_cast<s16x8*>(&xnT[((size_t)(b*N_ + n0 + nl))*C_ + c0 + cs]) = o;
  }
}

// ---------------- qkv GEMM: 256x256 tile, 8 waves, __syncthreads dbuf ----------------
// DIAGNOSTIC VARIANT: plain __syncthreads() double-buffer (R4-R6-proven structure),
// no inline-asm barriers/vmcnt. Keeps R7's fragment dedup (8 hoisted B reads +
// 2 x {8 A reads + 32 MFMA} per K-tile) and the fused vT epilogue.
__global__ __launch_bounds__(512, 2) void gemm_qkv8(const u16* __restrict__ A,
                                                    const u16* __restrict__ Bm,
                                                    const float* __restrict__ bias,
                                                    u16* __restrict__ Oq,
                                                    u16* __restrict__ Ok,
                                                    u16* __restrict__ OvT) {
  const int lda = 512, ldb = 512;
  __shared__ u16 smem[4][16384];   // As = smem[0..1], Bs = smem[2..3]; epilogue T aliases
  int tid = threadIdx.x, wid = tid >> 6, lane = tid & 63;
  int wr = wid >> 2, wc = wid & 3;           // 2M x 4N wave grid
  int m0 = blockIdx.x * 256, n0 = blockIdx.y * 256;

  f32x4 acc[8][4] = {};
  int sr = lane >> 3;                        // row within 8-row chunk
  int sg = (lane & 7) ^ sr;                  // pre-swizzled global k-slot

  auto stage = [&](int buf, int k0) {
#pragma unroll
    for (int t = 0; t < 4; ++t) {
      int chunk = wid*4 + t;                 // 0..31 (8 rows each, 256 rows)
      gl2lds16(A  + (size_t)(m0 + chunk*8 + sr)*lda + k0 + sg*8,
               (void*)(&smem[0 + buf][chunk*512]));
      gl2lds16(Bm + (size_t)(n0 + chunk*8 + sr)*ldb + k0 + sg*8,
               (void*)(&smem[2 + buf][chunk*512]));
    }
  };  // 8 gl2lds per wave per tile

  stage(0, 0);
  __syncthreads();
  int cur = 0;
  for (int kt = 0; kt < 8; ++kt) {
    if (kt + 1 < 8) stage(cur ^ 1, (kt + 1) * 64);   // prefetch overlaps compute below

    // hoist ALL B fragments for this K-tile (8 reads)
    s16x8 bfr[4][2];
#pragma unroll
    for (int ni = 0; ni < 4; ++ni)
#pragma unroll
      for (int ks2 = 0; ks2 < 2; ++ks2) {
        int br = wc*64 + ni*16 + (lane & 15);
        int s  = ks2*4 + (lane >> 4);
        bfr[ni][ks2] = *reinterpret_cast<const s16x8*>(&smem[2 + cur][br*64 + ((s ^ (br & 7)) << 3)]);
      }
    // two A half-phases, 8 reads + 32 MFMA each
#pragma unroll
    for (int qa = 0; qa < 2; ++qa) {
      s16x8 af[4][2];
#pragma unroll
      for (int mi2 = 0; mi2 < 4; ++mi2)
#pragma unroll
        for (int ks2 = 0; ks2 < 2; ++ks2) {
          int ar = wr*128 + qa*64 + mi2*16 + (lane & 15);
          int s  = ks2*4 + (lane >> 4);
          af[mi2][ks2] = *reinterpret_cast<const s16x8*>(&smem[0 + cur][ar*64 + ((s ^ (ar & 7)) << 3)]);
        }
      __builtin_amdgcn_s_setprio(1);
#pragma unroll
      for (int mi2 = 0; mi2 < 4; ++mi2)
#pragma unroll
        for (int ni = 0; ni < 4; ++ni)
#pragma unroll
          for (int ks2 = 0; ks2 < 2; ++ks2)
            acc[qa*4 + mi2][ni] =
              __builtin_amdgcn_mfma_f32_16x16x32_bf16(af[mi2][ks2], bfr[ni][ks2],
                                                      acc[qa*4 + mi2][ni], 0, 0, 0);
      __builtin_amdgcn_s_setprio(0);
    }

    __syncthreads();   // drains prefetch vmcnt (overlapped with MFMA) + LDS reads of buf
    cur ^= 1;
  }

  if (n0 < 1024) {
    // q/k: direct coalesced store
    u16* Odst; int cbase;
    if (n0 < 512) { Odst = Oq; cbase = n0; }
    else          { Odst = Ok; cbase = n0 - 512; }
#pragma unroll
    for (int mi = 0; mi < 8; ++mi) {
#pragma unroll
      for (int ni = 0; ni < 4; ++ni) {
        int cseg = cbase + wc*64 + ni*16 + (lane & 15);
        float bi = bias[n0 + wc*64 + ni*16 + (lane & 15)];
#pragma unroll
        for (int r = 0; r < 4; ++r) {
          int row = m0 + wr*128 + mi*16 + (lane >> 4)*4 + r;
          Odst[(size_t)row*512 + cseg] = f2b(acc[mi][ni][r] + bi);
        }
      }
    }
  } else {
    // v: transpose through LDS -> vT[b][d][n] coalesced. Two token-half passes.
    int cb = n0 - 1024;                 // 0 or 256
    int bidx = m0 >> 10;                // batch (m0 multiple of 256 -> single batch)
    int npart = m0 & 1023;              // token base within batch
    u16 (*T)[136] = reinterpret_cast<u16(*)[136]>(&smem[0][0]);   // [256 d][136] = 69.6 KB
#pragma unroll
    for (int h = 0; h < 2; ++h) {
      __syncthreads();                  // T free (main loop done / prev pass consumed)
      if (wr == h) {                    // this wave's 128 token-rows are in half h
#pragma unroll
        for (int mi = 0; mi < 8; ++mi)
#pragma unroll
          for (int ni = 0; ni < 4; ++ni) {
            int d = wc*64 + ni*16 + (lane & 15);
            float bi = bias[1024 + cb + d];
#pragma unroll
            for (int r = 0; r < 4; ++r) {
              int trow = mi*16 + (lane >> 4)*4 + r;   // 0..127 within half
              T[d][trow] = f2b(acc[mi][ni][r] + bi);
            }
          }
      }
      __syncthreads();
      // coalesced store: lanes 0..15 cover one d-row's 128 tokens (256B)
#pragma unroll
      for (int i = 0; i < 8; ++i) {
        int idx2 = tid + 512*i;
        int d  = idx2 >> 4;             // 0..255
        int ns = idx2 & 15;             // 16B segment within 128 tokens
        s16x8 vseg = *reinterpret_cast<const s16x8*>(&T[d][ns*8]);
        *reinterpret_cast<s16x8*>(&OvT[((size_t)(bidx*512 + cb + d))*1024 + npart + h*128 + ns*8]) = vseg;
      }
    }
  }
}

// ---------------- GEMM core (A K-contig, B^T K-contig), dbuf + swizzle ----------------
// EPI 1: bf16 out O0 [row][col], ld=N, batch strideC
// EPI 2: out[b][col][n] f32 = acc + bias[col] + residual bf16 from R (xnT [b][n][c])
template<int BM, int BN, int EPI>
__global__ __launch_bounds__(256) void gemm(const u16* __restrict__ A,
                                            const u16* __restrict__ Bm,
                                            int M, int N, int K, int lda, int ldb,
                                            long strideA, long strideB, long strideC,
                                            const float* __restrict__ bias,
                                            void* __restrict__ O0,
                                            const void* __restrict__ R) {
  constexpr int BK = 64;
  constexpr int MI = BM / 32, NI = BN / 32;
  __shared__ u16 As[2][BM*BK];
  __shared__ u16 Bs[2][BN*BK];
  int tid = threadIdx.x, wid = tid >> 6, lane = tid & 63;
  int m0 = blockIdx.x * BM, n0 = blockIdx.y * BN;
  const u16* Ab = A + (size_t)strideA * blockIdx.z;
  const u16* Bp = Bm + (size_t)strideB * blockIdx.z;

  f32x4 acc[MI][NI] = {};
  int wm = (wid >> 1) * (BM/2), wn = (wid & 1) * (BN/2);
  int sr = lane >> 3;
  int sg = (lane & 7) ^ sr;

  auto stage = [&](int buf, int k0) {
#pragma unroll
    for (int t = 0; t < BM/32; ++t) {
      int chunk = wid*(BM/32) + t;
      gl2lds16(Ab + (size_t)(m0 + chunk*8 + sr)*lda + k0 + sg*8,
               (void*)(&As[buf][chunk*512]));
    }
#pragma unroll
    for (int t = 0; t < BN/32; ++t) {
      int chunk = wid*(BN/32) + t;
      gl2lds16(Bp + (size_t)(n0 + chunk*8 + sr)*ldb + k0 + sg*8,
               (void*)(&Bs[buf][chunk*512]));
    }
  };

  int KT = K / BK;
  stage(0, 0);
  __syncthreads();
  int cur = 0;
  for (int kt = 0; kt < KT; ++kt) {
    if (kt + 1 < KT) stage(cur ^ 1, (kt + 1) * BK);
#pragma unroll
    for (int ks = 0; ks < BK; ks += 32) {
      int s = (ks >> 3) + (lane >> 4);
      s16x8 af[MI], bfr[NI];
#pragma unroll
      for (int mi = 0; mi < MI; ++mi) {
        int ar = wm + mi*16 + (lane & 15);
        af[mi] = *reinterpret_cast<const s16x8*>(&As[cur][ar*64 + ((s ^ (ar & 7)) << 3)]);
      }
#pragma unroll
      for (int ni = 0; ni < NI; ++ni) {
        int br = wn + ni*16 + (lane & 15);
        bfr[ni] = *reinterpret_cast<const s16x8*>(&Bs[cur][br*64 + ((s ^ (br & 7)) << 3)]);
      }
#pragma unroll
      for (int mi = 0; mi < MI; ++mi)
#pragma unroll
        for (int ni = 0; ni < NI; ++ni)
          acc[mi][ni] = __builtin_amdgcn_mfma_f32_16x16x32_bf16(af[mi], bfr[ni], acc[mi][ni], 0, 0, 0);
    }
    __syncthreads();
    cur ^= 1;
  }

#pragma unroll
  for (int mi = 0; mi < MI; ++mi) {
#pragma unroll
    for (int ni = 0; ni < NI; ++ni) {
      int col = n0 + wn + ni*16 + (lane & 15);
      if constexpr (EPI == 2) {
        int n = m0 + wm + mi*16 + (lane >> 4)*4;
        int b = blockIdx.z;
        const u16* xr = (const u16*)R + ((size_t)(b*N_ + n))*C_ + col;
        size_t idx = (size_t)b*524288 + (size_t)col*1024 + n;
        float bi = bias[col];
        float4 o;
        o.x = acc[mi][ni][0] + bi + b2f(xr[0]);
        o.y = acc[mi][ni][1] + bi + b2f(xr[512]);
        o.z = acc[mi][ni][2] + bi + b2f(xr[1024]);
        o.w = acc[mi][ni][3] + bi + b2f(xr[1536]);
        *reinterpret_cast<float4*>((float*)O0 + idx) = o;
      } else {
#pragma unroll
        for (int r = 0; r < 4; ++r) {
          int row = m0 + wm + mi*16 + (lane >> 4)*4 + r;
          ((u16*)O0)[(size_t)strideC*blockIdx.z + (size_t)row*N + col] = f2b(acc[mi][ni][r]);
        }
      }
    }
  }
}

// ---------------- mid: k softmax+transpose, q softmax ----------------
__global__ __launch_bounds__(256) void mid_kernel(const u16* __restrict__ kin,
                                                  u16* __restrict__ kT,
                                                  const u16* __restrict__ q,
                                                  u16* __restrict__ qs) {
  __shared__ __align__(16) char smem[33024];
  int bid = blockIdx.x;
  if (bid < 256) {
    // ---- k softmax + transpose: b = bid>>5, n0 = (bid&31)*32
    u16 (*T)[516] = (u16(*)[516])smem;
    int b = bid >> 5, n0 = (bid & 31) * 32;
    int wid = threadIdx.x >> 6, lane = threadIdx.x & 63;
#pragma unroll
    for (int i = 0; i < 8; ++i) {
      int r = wid * 8 + i;
      const u16* p = kin + ((size_t)(b*N_ + n0 + r))*C_;
      s16x8 raw = reinterpret_cast<const s16x8*>(p)[lane];
      float v[8]; float m = -3e38f;
#pragma unroll
      for (int j = 0; j < 8; ++j) { v[j] = b2f((u16)raw[j]); m = fmaxf(m, v[j]); }
      for (int off = 32; off; off >>= 1) m = fmaxf(m, __shfl_xor(m, off));
      float s = 0.f;
#pragma unroll
      for (int j = 0; j < 8; ++j) { v[j] = __expf(v[j] - m); s += v[j]; }
      for (int off = 32; off; off >>= 1) s += __shfl_xor(s, off);
      float inv = 1.f / s;
      union { s16x8 v8; unsigned long long d[2]; } o;
#pragma unroll
      for (int j = 0; j < 8; ++j) o.v8[j] = (short)f2b(v[j] * inv);
      unsigned long long* dst = reinterpret_cast<unsigned long long*>(&T[r][lane*8]);
      dst[0] = o.d[0]; dst[1] = o.d[1];
    }
    __syncthreads();
#pragma unroll
    for (int h = 0; h < 2; ++h) {
      int c = h*256 + threadIdx.x;
      u16* dst = kT + ((size_t)(b*C_ + c))*N_ + n0;
#pragma unroll
      for (int q4 = 0; q4 < 4; ++q4) {
        s16x8 o;
#pragma unroll
        for (int j = 0; j < 8; ++j) o[j] = (short)T[q4*8 + j][c];
        reinterpret_cast<s16x8*>(dst)[q4] = o;
      }
    }
  } else {
    // ---- q softmax over tokens: j = bid-256; b = j>>4, c0 = (j&15)*32
    float (*Mr)[65] = (float(*)[65])smem;
    float (*Sr)[65] = (float(*)[65])(smem + 8320);
    float (*MS)[2]  = (float(*)[2]) (smem + 16640);
    int j2 = bid - 256;
    int b = j2 >> 4, c0 = (j2 & 15) * 32;
    int t = threadIdx.x;
    int cg = t & 3;
    int rw = t >> 2;
    const u16* base = q + (size_t)b*N_*C_ + c0 + cg*8;
    float m[8], s[8];
#pragma unroll
    for (int j = 0; j < 8; ++j) { m[j] = -3e38f; s[j] = 0.f; }
    for (int it = 0; it < 16; ++it) {
      int n = it*64 + rw;
      s16x8 raw = *reinterpret_cast<const s16x8*>(base + (size_t)n*C_);
#pragma unroll
      for (int j = 0; j < 8; ++j) {
        float v = b2f((u16)raw[j]);
        float nm = fmaxf(m[j], v);
        s[j] = s[j]*__expf(m[j] - nm) + __expf(v - nm);
        m[j] = nm;
      }
    }
#pragma unroll
    for (int j = 0; j < 8; ++j) { Mr[cg*8 + j][rw] = m[j]; Sr[cg*8 + j][rw] = s[j]; }
    __syncthreads();
    if (t < 32) {
      float M = -3e38f;
      for (int i = 0; i < 64; ++i) M = fmaxf(M, Mr[t][i]);
      float S = 0.f;
      for (int i = 0; i < 64; ++i) S += Sr[t][i]*__expf(Mr[t][i] - M);
      MS[t][0] = M; MS[t][1] = 1.f / S;
    }
    __syncthreads();
    float Mv[8], Iv[8];
#pragma unroll
    for (int j = 0; j < 8; ++j) { Mv[j] = MS[cg*8 + j][0]; Iv[j] = MS[cg*8 + j][1]; }
    u16* ob = qs + (size_t)b*N_*C_ + c0 + cg*8;
    for (int it = 0; it < 16; ++it) {
      int n = it*64 + rw;
      s16x8 raw = *reinterpret_cast<const s16x8*>(base + (size_t)n*C_);
      s16x8 o;
#pragma unroll
      for (int j = 0; j < 8; ++j)
        o[j] = (short)f2b(__expf(b2f((u16)raw[j]) - Mv[j]) * Iv[j]);
      *reinterpret_cast<s16x8*>(ob + (size_t)n*C_) = o;
    }
  }
}

// ---------------- launch ----------------
extern "C" void kernel_launch(void* const* d_in, const int* in_sizes, int n_in,
                              void* d_out, int out_size, void* d_ws, size_t ws_size,
                              hipStream_t stream) {
  (void)in_sizes; (void)n_in; (void)out_size; (void)ws_size;
  const float* x      = (const float*)d_in[0];
  const float* gn_w   = (const float*)d_in[1];
  const float* gn_b   = (const float*)d_in[2];
  const float* qkv_w  = (const float*)d_in[3];
  const float* qkv_b  = (const float*)d_in[4];
  const float* proj_w = (const float*)d_in[5];
  const float* proj_b = (const float*)d_in[6];

  char* ws = (char*)d_ws;
  u16*   xnT  = (u16*)  (ws + OFF_XNT);
  u16*   qb   = (u16*)  (ws + OFF_Q);
  u16*   kb   = (u16*)  (ws + OFF_K);
  u16*   kT   = (u16*)  (ws + OFF_KT);
  u16*   vT   = (u16*)  (ws + OFF_VT);
  u16*   qsb  = (u16*)  (ws + OFF_QS);
  u16*   ctx  = (u16*)  (ws + OFF_CTX);
  u16*   mt   = (u16*)  (ws + OFF_MT);
  u16*   wq   = (u16*)  (ws + OFF_WQ);
  u16*   wp   = (u16*)  (ws + OFF_WP);
  float* gnp  = (float*)(ws + OFF_GNP);

  pre_kernel<<<dim3(1536), 256, 0, stream>>>(x, gnp, qkv_w, proj_w, wq, wp);
  gn_apply<<<dim3(8, 8, 16), 256, 0, stream>>>(x, gn_w, gn_b, gnp, xnT);

  // qkv: q,k bf16 [tok][c]; v written directly as vT [b][d][n]
  gemm_qkv8<<<dim3(32, 6), 512, 0, stream>>>(xnT, wq, qkv_b, qb, kb, vT);

  // k softmax+T, q softmax
  mid_kernel<<<dim3(384), 256, 0, stream>>>(kb, kT, qb, qsb);

  // ctx[b][c][d] = sum_n kT[b][c][n] * vT[b][d][n]
  gemm<64,64,1><<<dim3(8, 8, 8), 256, 0, stream>>>(kT, vT, 512, 512, 1024, 1024, 1024,
                                                   524288, 524288, 262144, nullptr, ctx, nullptr);
  // MT[b][e][c] = sum_d wp[e][d] * ctx[b][c][d]
  gemm<64,64,1><<<dim3(8, 8, 8), 256, 0, stream>>>(wp, ctx, 512, 512, 512, 512, 512,
                                                   0, 262144, 262144, nullptr, mt, nullptr);
  // out[b][e][n] = sum_c qs[b][n][c] * MT[b][e][c] + proj_b[e] + xn
  gemm<64,64,2><<<dim3(16, 8, 8), 256, 0, stream>>>(qsb, mt, 1024, 512, 512, 512, 512,
                                                    524288, 262144, 0, proj_b, (float*)d_out, xnT);
}

// Round 12
// 154.441 us; speedup vs baseline: 1.4037x; 1.0046x over previous
//
#include <hip/hip_runtime.h>
#include <hip/hip_bf16.h>
#include <stdint.h>

typedef unsigned short u16;
typedef __attribute__((ext_vector_type(8))) short s16x8;
typedef __attribute__((ext_vector_type(4))) float f32x4;
typedef __attribute__((ext_vector_type(4))) unsigned short u16x4;

static constexpr int B_ = 8, C_ = 512, N_ = 1024, G_ = 8;
static constexpr float EPS = 1e-5f;

// ---------------- workspace layout (bytes) ----------------
static constexpr size_t OFF_XNT  = 0;                                   // bf16 [B][N][C] groupnorm out
static constexpr size_t OFF_Q    = OFF_XNT  + (size_t)B_*N_*C_*2;       // bf16 [B][N][C] q raw
static constexpr size_t OFF_KTR  = OFF_Q    + (size_t)B_*N_*C_*2;       // bf16 [B][C][N] k raw transposed (qkv8)
static constexpr size_t OFF_KT   = OFF_KTR  + (size_t)B_*N_*C_*2;       // bf16 [B][C][N] softmax(k)^T
static constexpr size_t OFF_VT   = OFF_KT   + (size_t)B_*N_*C_*2;       // bf16 [B][C][N] v^T (qkv8)
static constexpr size_t OFF_QS   = OFF_VT   + (size_t)B_*N_*C_*2;       // bf16 [B][N][C] softmax(q)
static constexpr size_t OFF_CTX  = OFF_QS   + (size_t)B_*N_*C_*2;       // bf16 [B][C][C] ctx [c][d]
static constexpr size_t OFF_MT   = OFF_CTX  + (size_t)B_*C_*C_*2;       // bf16 [B][C][C] (ctx@wp^T)^T : [e][c]
static constexpr size_t OFF_WQ   = OFF_MT   + (size_t)B_*C_*C_*2;       // bf16 [1536][512]
static constexpr size_t OFF_WP   = OFF_WQ   + (size_t)3*C_*C_*2;        // bf16 [512][512]
static constexpr size_t OFF_GNP  = OFF_WP   + (size_t)C_*C_*2;          // f32 [64][8][2]

// ---------------- helpers ----------------
__device__ __forceinline__ float b2f(u16 u) {
  union { float f; uint32_t i; } x; x.i = ((uint32_t)u) << 16; return x.f;
}
__device__ __forceinline__ u16 f2b(float f) {
  union { float f; uint32_t i; } x; x.f = f;
  return (u16)((x.i + 0x7fffu + ((x.i >> 16) & 1u)) >> 16);
}
#define AS1 __attribute__((address_space(1)))
#define AS3 __attribute__((address_space(3)))
__device__ __forceinline__ void gl2lds16(const void* g, void* l) {
  __builtin_amdgcn_global_load_lds((const AS1 void*)g, (AS3 void*)l, 16, 0, 0);
}

// ---------------- pre: groupnorm partial sums + weight conversion ----------------
__global__ __launch_bounds__(256) void pre_kernel(const float* __restrict__ x,
                                                  float* __restrict__ gnp,
                                                  const float* __restrict__ w1,
                                                  const float* __restrict__ w2,
                                                  u16* __restrict__ o1,
                                                  u16* __restrict__ o2) {
  int bid = blockIdx.x;
  if (bid < 512) {
    int bg = bid >> 3, chunk = bid & 7;
    const float4* p = reinterpret_cast<const float4*>(x + (size_t)bg * 65536 + (size_t)chunk * 8192);
    int tid = threadIdx.x;
    float s = 0.f, sq = 0.f;
#pragma unroll
    for (int i = 0; i < 8; ++i) {
      float4 v = p[i * 256 + tid];
      s  += v.x + v.y + v.z + v.w;
      sq += v.x*v.x + v.y*v.y + v.z*v.z + v.w*v.w;
    }
    for (int off = 32; off; off >>= 1) { s += __shfl_xor(s, off); sq += __shfl_xor(sq, off); }
    __shared__ float red[8];
    int wid = tid >> 6, lane = tid & 63;
    if (lane == 0) { red[wid*2] = s; red[wid*2+1] = sq; }
    __syncthreads();
    if (tid == 0) {
      gnp[(bg*8 + chunk)*2 + 0] = red[0]+red[2]+red[4]+red[6];
      gnp[(bg*8 + chunk)*2 + 1] = red[1]+red[3]+red[5]+red[7];
    }
  } else {
    int i = (bid - 512) * 256 + threadIdx.x;
    const int n1 = 1536*512/4;
    if (i < n1) {
      float4 v = reinterpret_cast<const float4*>(w1)[i];
      u16x4 r = { f2b(v.x), f2b(v.y), f2b(v.z), f2b(v.w) };
      reinterpret_cast<u16x4*>(o1)[i] = r;
    } else {
      int j = i - n1;
      float4 v = reinterpret_cast<const float4*>(w2)[j];
      u16x4 r = { f2b(v.x), f2b(v.y), f2b(v.z), f2b(v.w) };
      reinterpret_cast<u16x4*>(o2)[j] = r;
    }
  }
}

// reads x [b][c][n], writes xnT bf16 [b][n][c]
__global__ __launch_bounds__(256) void gn_apply(const float* __restrict__ x,
                                                const float* __restrict__ gw,
                                                const float* __restrict__ gb,
                                                const float* __restrict__ gnp,
                                                u16* __restrict__ xnT) {
  __shared__ float T[64][65];
  int b = blockIdx.x, c0 = blockIdx.y * 64, n0 = blockIdx.z * 64;
  int bg = b * G_ + blockIdx.y;
  float S = 0.f, SQ = 0.f;
#pragma unroll
  for (int i = 0; i < 8; ++i) { S += gnp[(bg*8+i)*2]; SQ += gnp[(bg*8+i)*2+1]; }
  float mean = S * (1.f/65536.f);
  float var  = SQ * (1.f/65536.f) - mean*mean;
  float rstd = rsqrtf(var + EPS);
  int tn = threadIdx.x & 63, tc = threadIdx.x >> 6;
#pragma unroll 4
  for (int it = 0; it < 16; ++it) {
    int cl = it*4 + tc;
    int c = c0 + cl;
    float v = x[((size_t)b*C_ + c)*N_ + n0 + tn];
    T[tn][cl] = (v - mean) * rstd * gw[c] + gb[c];
  }
  __syncthreads();
#pragma unroll
  for (int p = 0; p < 2; ++p) {
    int nl = p*32 + (threadIdx.x >> 3);
    int cs = (threadIdx.x & 7) * 8;
    s16x8 o;
#pragma unroll
    for (int j = 0; j < 8; ++j) o[j] = (short)f2b(T[nl][cs + j]);
    *reinterpret_cast<s16x8*>(&xnT[((size_t)(b*N_ + n0 + nl))*C_ + c0 + cs]) = o;
  }
}

// ---------------- qkv GEMM: 256x256 tile, 8 waves, __syncthreads dbuf ----------------
// Per K-tile per wave: 8 B-frag reads (hoisted) + 2 x {8 A-frag reads + 32 MFMA}.
// k-blocks (n0 in [512,1024)) and v-blocks (n0 >= 1024) write transposed output
// [b][col][n] via LDS transpose (aliased onto staging buffers) -> coalesced 256B rows.
__global__ __launch_bounds__(512, 2) void gemm_qkv8(const u16* __restrict__ A,
                                                    const u16* __restrict__ Bm,
                                                    const float* __restrict__ bias,
                                                    u16* __restrict__ Oq,
                                                    u16* __restrict__ OkTr,
                                                    u16* __restrict__ OvT) {
  const int lda = 512, ldb = 512;
  __shared__ u16 smem[4][16384];   // As = smem[0..1], Bs = smem[2..3]; epilogue T aliases
  int tid = threadIdx.x, wid = tid >> 6, lane = tid & 63;
  int wr = wid >> 2, wc = wid & 3;           // 2M x 4N wave grid
  int m0 = blockIdx.x * 256, n0 = blockIdx.y * 256;

  f32x4 acc[8][4] = {};
  int sr = lane >> 3;                        // row within 8-row chunk
  int sg = (lane & 7) ^ sr;                  // pre-swizzled global k-slot

  auto stage = [&](int buf, int k0) {
#pragma unroll
    for (int t = 0; t < 4; ++t) {
      int chunk = wid*4 + t;                 // 0..31 (8 rows each, 256 rows)
      gl2lds16(A  + (size_t)(m0 + chunk*8 + sr)*lda + k0 + sg*8,
               (void*)(&smem[0 + buf][chunk*512]));
      gl2lds16(Bm + (size_t)(n0 + chunk*8 + sr)*ldb + k0 + sg*8,
               (void*)(&smem[2 + buf][chunk*512]));
    }
  };  // 8 gl2lds per wave per tile

  stage(0, 0);
  __syncthreads();
  int cur = 0;
  for (int kt = 0; kt < 8; ++kt) {
    if (kt + 1 < 8) stage(cur ^ 1, (kt + 1) * 64);   // prefetch overlaps compute below

    // hoist ALL B fragments for this K-tile (8 reads)
    s16x8 bfr[4][2];
#pragma unroll
    for (int ni = 0; ni < 4; ++ni)
#pragma unroll
      for (int ks2 = 0; ks2 < 2; ++ks2) {
        int br = wc*64 + ni*16 + (lane & 15);
        int s  = ks2*4 + (lane >> 4);
        bfr[ni][ks2] = *reinterpret_cast<const s16x8*>(&smem[2 + cur][br*64 + ((s ^ (br & 7)) << 3)]);
      }
    // two A half-phases, 8 reads + 32 MFMA each
#pragma unroll
    for (int qa = 0; qa < 2; ++qa) {
      s16x8 af[4][2];
#pragma unroll
      for (int mi2 = 0; mi2 < 4; ++mi2)
#pragma unroll
        for (int ks2 = 0; ks2 < 2; ++ks2) {
          int ar = wr*128 + qa*64 + mi2*16 + (lane & 15);
          int s  = ks2*4 + (lane >> 4);
          af[mi2][ks2] = *reinterpret_cast<const s16x8*>(&smem[0 + cur][ar*64 + ((s ^ (ar & 7)) << 3)]);
        }
      __builtin_amdgcn_s_setprio(1);
#pragma unroll
      for (int mi2 = 0; mi2 < 4; ++mi2)
#pragma unroll
        for (int ni = 0; ni < 4; ++ni)
#pragma unroll
          for (int ks2 = 0; ks2 < 2; ++ks2)
            acc[qa*4 + mi2][ni] =
              __builtin_amdgcn_mfma_f32_16x16x32_bf16(af[mi2][ks2], bfr[ni][ks2],
                                                      acc[qa*4 + mi2][ni], 0, 0, 0);
      __builtin_amdgcn_s_setprio(0);
    }

    __syncthreads();   // drains prefetch vmcnt (overlapped with MFMA) + LDS reads of buf
    cur ^= 1;
  }

  if (n0 < 512) {
    // q: direct coalesced store [tok][c]
#pragma unroll
    for (int mi = 0; mi < 8; ++mi) {
#pragma unroll
      for (int ni = 0; ni < 4; ++ni) {
        int c = n0 + wc*64 + ni*16 + (lane & 15);
        float bi = bias[c];
#pragma unroll
        for (int r = 0; r < 4; ++r) {
          int row = m0 + wr*128 + mi*16 + (lane >> 4)*4 + r;
          Oq[(size_t)row*512 + c] = f2b(acc[mi][ni][r] + bi);
        }
      }
    }
  } else {
    // k or v: transpose through LDS -> [b][col][n] coalesced. Two token-half passes.
    u16* dstT = (n0 < 1024) ? OkTr : OvT;
    int cb = n0 - ((n0 < 1024) ? 512 : 1024);   // 0 or 256
    int bidx = m0 >> 10;                 // batch (256-token tile within one batch)
    int npart = m0 & 1023;               // token base within batch
    u16 (*T)[136] = reinterpret_cast<u16(*)[136]>(&smem[0][0]);   // [256 d][136] = 69.6 KB
#pragma unroll
    for (int h = 0; h < 2; ++h) {
      __syncthreads();                  // T free (main loop done / prev pass consumed)
      if (wr == h) {                    // this wave's 128 token-rows are in half h
#pragma unroll
        for (int mi = 0; mi < 8; ++mi)
#pragma unroll
          for (int ni = 0; ni < 4; ++ni) {
            int d = wc*64 + ni*16 + (lane & 15);
            float bi = bias[n0 + d];
#pragma unroll
            for (int r = 0; r < 4; ++r) {
              int trow = mi*16 + (lane >> 4)*4 + r;   // 0..127 within half
              T[d][trow] = f2b(acc[mi][ni][r] + bi);
            }
          }
      }
      __syncthreads();
      // coalesced store: lanes 0..15 cover one d-row's 128 tokens (256B)
#pragma unroll
      for (int i = 0; i < 8; ++i) {
        int idx2 = tid + 512*i;
        int d  = idx2 >> 4;             // 0..255
        int ns = idx2 & 15;             // 16B segment within 128 tokens
        s16x8 vseg = *reinterpret_cast<const s16x8*>(&T[d][ns*8]);
        *reinterpret_cast<s16x8*>(&dstT[((size_t)(bidx*512 + cb + d))*1024 + npart + h*128 + ns*8]) = vseg;
      }
    }
  }
}

// ---------------- GEMM core (A K-contig, B^T K-contig), dbuf + swizzle ----------------
// EPI 1: bf16 out O0 [row][col], ld=N, batch strideC
// EPI 2: out[b][col][n] f32 = acc + bias[col] + residual bf16 from R (xnT [b][n][c])
template<int BM, int BN, int EPI>
__global__ __launch_bounds__(256) void gemm(const u16* __restrict__ A,
                                            const u16* __restrict__ Bm,
                                            int M, int N, int K, int lda, int ldb,
                                            long strideA, long strideB, long strideC,
                                            const float* __restrict__ bias,
                                            void* __restrict__ O0,
                                            const void* __restrict__ R) {
  constexpr int BK = 64;
  constexpr int MI = BM / 32, NI = BN / 32;
  __shared__ u16 As[2][BM*BK];
  __shared__ u16 Bs[2][BN*BK];
  int tid = threadIdx.x, wid = tid >> 6, lane = tid & 63;
  int m0 = blockIdx.x * BM, n0 = blockIdx.y * BN;
  const u16* Ab = A + (size_t)strideA * blockIdx.z;
  const u16* Bp = Bm + (size_t)strideB * blockIdx.z;

  f32x4 acc[MI][NI] = {};
  int wm = (wid >> 1) * (BM/2), wn = (wid & 1) * (BN/2);
  int sr = lane >> 3;
  int sg = (lane & 7) ^ sr;

  auto stage = [&](int buf, int k0) {
#pragma unroll
    for (int t = 0; t < BM/32; ++t) {
      int chunk = wid*(BM/32) + t;
      gl2lds16(Ab + (size_t)(m0 + chunk*8 + sr)*lda + k0 + sg*8,
               (void*)(&As[buf][chunk*512]));
    }
#pragma unroll
    for (int t = 0; t < BN/32; ++t) {
      int chunk = wid*(BN/32) + t;
      gl2lds16(Bp + (size_t)(n0 + chunk*8 + sr)*ldb + k0 + sg*8,
               (void*)(&Bs[buf][chunk*512]));
    }
  };

  int KT = K / BK;
  stage(0, 0);
  __syncthreads();
  int cur = 0;
  for (int kt = 0; kt < KT; ++kt) {
    if (kt + 1 < KT) stage(cur ^ 1, (kt + 1) * BK);
#pragma unroll
    for (int ks = 0; ks < BK; ks += 32) {
      int s = (ks >> 3) + (lane >> 4);
      s16x8 af[MI], bfr[NI];
#pragma unroll
      for (int mi = 0; mi < MI; ++mi) {
        int ar = wm + mi*16 + (lane & 15);
        af[mi] = *reinterpret_cast<const s16x8*>(&As[cur][ar*64 + ((s ^ (ar & 7)) << 3)]);
      }
#pragma unroll
      for (int ni = 0; ni < NI; ++ni) {
        int br = wn + ni*16 + (lane & 15);
        bfr[ni] = *reinterpret_cast<const s16x8*>(&Bs[cur][br*64 + ((s ^ (br & 7)) << 3)]);
      }
#pragma unroll
      for (int mi = 0; mi < MI; ++mi)
#pragma unroll
        for (int ni = 0; ni < NI; ++ni)
          acc[mi][ni] = __builtin_amdgcn_mfma_f32_16x16x32_bf16(af[mi], bfr[ni], acc[mi][ni], 0, 0, 0);
    }
    __syncthreads();
    cur ^= 1;
  }

#pragma unroll
  for (int mi = 0; mi < MI; ++mi) {
#pragma unroll
    for (int ni = 0; ni < NI; ++ni) {
      int col = n0 + wn + ni*16 + (lane & 15);
      if constexpr (EPI == 2) {
        int n = m0 + wm + mi*16 + (lane >> 4)*4;
        int b = blockIdx.z;
        const u16* xr = (const u16*)R + ((size_t)(b*N_ + n))*C_ + col;
        size_t idx = (size_t)b*524288 + (size_t)col*1024 + n;
        float bi = bias[col];
        float4 o;
        o.x = acc[mi][ni][0] + bi + b2f(xr[0]);
        o.y = acc[mi][ni][1] + bi + b2f(xr[512]);
        o.z = acc[mi][ni][2] + bi + b2f(xr[1024]);
        o.w = acc[mi][ni][3] + bi + b2f(xr[1536]);
        *reinterpret_cast<float4*>((float*)O0 + idx) = o;
      } else {
#pragma unroll
        for (int r = 0; r < 4; ++r) {
          int row = m0 + wm + mi*16 + (lane >> 4)*4 + r;
          ((u16*)O0)[(size_t)strideC*blockIdx.z + (size_t)row*N + col] = f2b(acc[mi][ni][r]);
        }
      }
    }
  }
}

// ---------------- mid: k column-softmax (kTraw->kT) + q column-softmax ----------------
// k: softmax over c for fixed (b,n) on [b][c][n] layout -> coalesced 128B reads per c,
//    coalesced 16B/thread writes. q: softmax over tokens (unchanged structure).
__global__ __launch_bounds__(256) void mid_kernel(const u16* __restrict__ kTraw,
                                                  u16* __restrict__ kT,
                                                  const u16* __restrict__ q,
                                                  u16* __restrict__ qs) {
  __shared__ __align__(16) char smem[33024];
  int bid = blockIdx.x;
  int t = threadIdx.x;
  if (bid < 128) {
    // ---- k column softmax: b = bid>>4, n-tile of 64 = (bid&15)*64
    float (*Mr)[64] = (float(*)[64])smem;            // [32 cgrp][64 n]
    float (*Sr)[64] = (float(*)[64])(smem + 8192);
    float (*MS)[2]  = (float(*)[2]) (smem + 16384);  // [64 n][2]
    int b = bid >> 4, n0 = (bid & 15) * 64;
    int nseg = t & 7;            // 8 segs x 8 tokens = 64 tokens
    int cgrp = t >> 3;           // 32 groups x 16 c = 512 c
    const u16* base = kTraw + (size_t)b*C_*N_ + n0 + nseg*8;
    float m[8], s[8];
#pragma unroll
    for (int j = 0; j < 8; ++j) { m[j] = -3e38f; s[j] = 0.f; }
    for (int i = 0; i < 16; ++i) {
      int c = cgrp*16 + i;
      s16x8 raw = *reinterpret_cast<const s16x8*>(base + (size_t)c*N_);
#pragma unroll
      for (int j = 0; j < 8; ++j) {
        float v = b2f((u16)raw[j]);
        float nm = fmaxf(m[j], v);
        s[j] = s[j]*__expf(m[j] - nm) + __expf(v - nm);
        m[j] = nm;
      }
    }
#pragma unroll
    for (int j = 0; j < 8; ++j) { Mr[cgrp][nseg*8 + j] = m[j]; Sr[cgrp][nseg*8 + j] = s[j]; }
    __syncthreads();
    if (t < 64) {
      float M = -3e38f;
      for (int g = 0; g < 32; ++g) M = fmaxf(M, Mr[g][t]);
      float S = 0.f;
      for (int g = 0; g < 32; ++g) S += Sr[g][t]*__expf(Mr[g][t] - M);
      MS[t][0] = M; MS[t][1] = 1.f / S;
    }
    __syncthreads();
    float Mv[8], Iv[8];
#pragma unroll
    for (int j = 0; j < 8; ++j) { Mv[j] = MS[nseg*8 + j][0]; Iv[j] = MS[nseg*8 + j][1]; }
    u16* ob = kT + (size_t)b*C_*N_ + n0 + nseg*8;
    for (int i = 0; i < 16; ++i) {
      int c = cgrp*16 + i;
      s16x8 raw = *reinterpret_cast<const s16x8*>(base + (size_t)c*N_);
      s16x8 o;
#pragma unroll
      for (int j = 0; j < 8; ++j)
        o[j] = (short)f2b(__expf(b2f((u16)raw[j]) - Mv[j]) * Iv[j]);
      *reinterpret_cast<s16x8*>(ob + (size_t)c*N_) = o;
    }
  } else {
    // ---- q softmax over tokens: j2 = bid-128; b = j2>>4, c0 = (j2&15)*32
    float (*Mr)[65] = (float(*)[65])smem;
    float (*Sr)[65] = (float(*)[65])(smem + 8320);
    float (*MS)[2]  = (float(*)[2]) (smem + 16640);
    int j2 = bid - 128;
    int b = j2 >> 4, c0 = (j2 & 15) * 32;
    int cg = t & 3;
    int rw = t >> 2;
    const u16* base = q + (size_t)b*N_*C_ + c0 + cg*8;
    float m[8], s[8];
#pragma unroll
    for (int j = 0; j < 8; ++j) { m[j] = -3e38f; s[j] = 0.f; }
    for (int it = 0; it < 16; ++it) {
      int n = it*64 + rw;
      s16x8 raw = *reinterpret_cast<const s16x8*>(base + (size_t)n*C_);
#pragma unroll
      for (int j = 0; j < 8; ++j) {
        float v = b2f((u16)raw[j]);
        float nm = fmaxf(m[j], v);
        s[j] = s[j]*__expf(m[j] - nm) + __expf(v - nm);
        m[j] = nm;
      }
    }
#pragma unroll
    for (int j = 0; j < 8; ++j) { Mr[cg*8 + j][rw] = m[j]; Sr[cg*8 + j][rw] = s[j]; }
    __syncthreads();
    if (t < 32) {
      float M = -3e38f;
      for (int i = 0; i < 64; ++i) M = fmaxf(M, Mr[t][i]);
      float S = 0.f;
      for (int i = 0; i < 64; ++i) S += Sr[t][i]*__expf(Mr[t][i] - M);
      MS[t][0] = M; MS[t][1] = 1.f / S;
    }
    __syncthreads();
    float Mv[8], Iv[8];
#pragma unroll
    for (int j = 0; j < 8; ++j) { Mv[j] = MS[cg*8 + j][0]; Iv[j] = MS[cg*8 + j][1]; }
    u16* ob = qs + (size_t)b*N_*C_ + c0 + cg*8;
    for (int it = 0; it < 16; ++it) {
      int n = it*64 + rw;
      s16x8 raw = *reinterpret_cast<const s16x8*>(base + (size_t)n*C_);
      s16x8 o;
#pragma unroll
      for (int j = 0; j < 8; ++j)
        o[j] = (short)f2b(__expf(b2f((u16)raw[j]) - Mv[j]) * Iv[j]);
      *reinterpret_cast<s16x8*>(ob + (size_t)n*C_) = o;
    }
  }
}

// ---------------- launch ----------------
extern "C" void kernel_launch(void* const* d_in, const int* in_sizes, int n_in,
                              void* d_out, int out_size, void* d_ws, size_t ws_size,
                              hipStream_t stream) {
  (void)in_sizes; (void)n_in; (void)out_size; (void)ws_size;
  const float* x      = (const float*)d_in[0];
  const float* gn_w   = (const float*)d_in[1];
  const float* gn_b   = (const float*)d_in[2];
  const float* qkv_w  = (const float*)d_in[3];
  const float* qkv_b  = (const float*)d_in[4];
  const float* proj_w = (const float*)d_in[5];
  const float* proj_b = (const float*)d_in[6];

  char* ws = (char*)d_ws;
  u16*   xnT  = (u16*)  (ws + OFF_XNT);
  u16*   qb   = (u16*)  (ws + OFF_Q);
  u16*   kTr  = (u16*)  (ws + OFF_KTR);
  u16*   kT   = (u16*)  (ws + OFF_KT);
  u16*   vT   = (u16*)  (ws + OFF_VT);
  u16*   qsb  = (u16*)  (ws + OFF_QS);
  u16*   ctx  = (u16*)  (ws + OFF_CTX);
  u16*   mt   = (u16*)  (ws + OFF_MT);
  u16*   wq   = (u16*)  (ws + OFF_WQ);
  u16*   wp   = (u16*)  (ws + OFF_WP);
  float* gnp  = (float*)(ws + OFF_GNP);

  pre_kernel<<<dim3(1536), 256, 0, stream>>>(x, gnp, qkv_w, proj_w, wq, wp);
  gn_apply<<<dim3(8, 8, 16), 256, 0, stream>>>(x, gn_w, gn_b, gnp, xnT);

  // qkv: q bf16 [tok][c]; k,v written transposed [b][col][n]
  gemm_qkv8<<<dim3(32, 6), 512, 0, stream>>>(xnT, wq, qkv_b, qb, kTr, vT);

  // k column-softmax (kTr -> kT), q softmax
  mid_kernel<<<dim3(256), 256, 0, stream>>>(kTr, kT, qb, qsb);

  // ctx[b][c][d] = sum_n kT[b][c][n] * vT[b][d][n]
  gemm<64,64,1><<<dim3(8, 8, 8), 256, 0, stream>>>(kT, vT, 512, 512, 1024, 1024, 1024,
                                                   524288, 524288, 262144, nullptr, ctx, nullptr);
  // MT[b][e][c] = sum_d wp[e][d] * ctx[b][c][d]
  gemm<64,64,1><<<dim3(8, 8, 8), 256, 0, stream>>>(wp, ctx, 512, 512, 512, 512, 512,
                                                   0, 262144, 262144, nullptr, mt, nullptr);
  // out[b][e][n] = sum_c qs[b][n][c] * MT[b][e][c] + proj_b[e] + xn
  gemm<64,64,2><<<dim3(16, 8, 8), 256, 0, stream>>>(qsb, mt, 1024, 512, 512, 512, 512,
                                                    524288, 262144, 0, proj_b, (float*)d_out, xnT);
}